// Round 1
// baseline (730.535 us; speedup 1.0000x reference)
//
#include <hip/hip_runtime.h>
#include <hip/hip_bf16.h>

// GCN 2-layer: deg -> dinv -> CSR build (hist/scan/fill) -> [GEMM -> gather(+self+bias+relu)] x2 -> pool
// N = 100000, E = 1600000, F = 128, G = 64

__device__ __forceinline__ float4 ld4(const float* p) { return *(const float4*)p; }

// ---------------- degree + count histogram ----------------
__global__ __launch_bounds__(256) void k_hist(const int* __restrict__ dst,
                                              const float* __restrict__ w,
                                              float* __restrict__ deg,
                                              int* __restrict__ cnt, int E) {
    int e = blockIdx.x * 256 + threadIdx.x;
    if (e >= E) return;
    int d = dst[e];
    atomicAdd(&deg[d], w[e]);
    atomicAdd(&cnt[d], 1);
}

__global__ __launch_bounds__(256) void k_dinv(float* deg, int N) {
    int i = blockIdx.x * 256 + threadIdx.x;
    if (i < N) deg[i] = rsqrtf(deg[i] + 1.0f);   // self-loop weight 1.0
}

// ---------------- exclusive scan (two-level) ----------------
__global__ __launch_bounds__(256) void k_scan1(const int* __restrict__ cnt,
                                               int* __restrict__ rs,
                                               int* __restrict__ bsum, int N) {
    __shared__ int wsum[4];
    int tid = threadIdx.x;
    int base = blockIdx.x * 1024 + tid * 4;
    int v0 = 0, v1 = 0, v2 = 0, v3 = 0;
    if (base + 3 < N) {
        int4 t = *(const int4*)&cnt[base];
        v0 = t.x; v1 = t.y; v2 = t.z; v3 = t.w;
    } else {
        if (base + 0 < N) v0 = cnt[base + 0];
        if (base + 1 < N) v1 = cnt[base + 1];
        if (base + 2 < N) v2 = cnt[base + 2];
        if (base + 3 < N) v3 = cnt[base + 3];
    }
    int ts = v0 + v1 + v2 + v3;
    int lane = tid & 63;
    int x = ts;
    #pragma unroll
    for (int off = 1; off < 64; off <<= 1) {
        int y = __shfl_up(x, off);
        if (lane >= off) x += y;
    }
    int wid = tid >> 6;
    if (lane == 63) wsum[wid] = x;
    __syncthreads();
    int woff = 0;
    for (int wI = 0; wI < wid; ++wI) woff += wsum[wI];
    int start = woff + x - ts;  // exclusive prefix of this thread's chunk (within block)
    int o0 = start, o1 = start + v0, o2 = start + v0 + v1, o3 = start + v0 + v1 + v2;
    if (base + 3 < N) {
        *(int4*)&rs[base] = make_int4(o0, o1, o2, o3);
    } else {
        if (base + 0 < N) rs[base + 0] = o0;
        if (base + 1 < N) rs[base + 1] = o1;
        if (base + 2 < N) rs[base + 2] = o2;
        if (base + 3 < N) rs[base + 3] = o3;
    }
    if (tid == 255) bsum[blockIdx.x] = woff + x;  // block total
}

__global__ void k_scan2(int* bsum, int nb) {   // single wave
    int lane = threadIdx.x;
    int carry = 0;
    for (int b = 0; b < nb; b += 64) {
        int i = b + lane;
        int v = (i < nb) ? bsum[i] : 0;
        int x = v;
        #pragma unroll
        for (int off = 1; off < 64; off <<= 1) {
            int y = __shfl_up(x, off);
            if (lane >= off) x += y;
        }
        int tot = __shfl(x, 63);
        if (i < nb) bsum[i] = carry + x - v;   // exclusive
        carry += tot;
    }
}

__global__ __launch_bounds__(256) void k_scan3(int* __restrict__ rs, int* __restrict__ cur,
                                               const int* __restrict__ bsum, int N, int E) {
    int i = blockIdx.x * 256 + threadIdx.x;
    if (i < N) {
        int v = rs[i] + bsum[i >> 10];
        rs[i] = v;
        cur[i] = v;
    }
    if (i == 0) rs[N] = E;
}

// ---------------- CSR bucket fill (norm computed inline) ----------------
__global__ __launch_bounds__(256) void k_fill(const int* __restrict__ src,
                                              const int* __restrict__ dst,
                                              const float* __restrict__ w,
                                              const float* __restrict__ dinv,
                                              int* __restrict__ cur,
                                              int* __restrict__ csrc,
                                              float* __restrict__ cw, int E) {
    int e = blockIdx.x * 256 + threadIdx.x;
    if (e >= E) return;
    int s = src[e], d = dst[e];
    int pos = atomicAdd(&cur[d], 1);
    csrc[pos] = s;
    cw[pos] = dinv[s] * w[e] * dinv[d];
}

// ---------------- GEMM: C[N,128] = A[N,128] @ W[128,128] ----------------
// 128x128 block tile, 8x8 per-thread micro-tile, 2 k-phases of 64 (LDS = 64KB exactly).
// X staged transposed with XOR swizzle to keep ds_read_b128 conflict-free.
__global__ __launch_bounds__(256, 1) void k_gemm(const float* __restrict__ A,
                                                 const float* __restrict__ W,
                                                 float* __restrict__ C, int nrows) {
    __shared__ float Wh[64 * 128];   // 32 KB: W rows of current k-phase
    __shared__ float Xt[64 * 128];   // 32 KB: X^T [kk][r], swizzled
    const int tid = threadIdx.x;
    const int row0 = blockIdx.x * 128;
    const int wave = tid >> 6, lane = tid & 63;
    const int r0 = (wave >> 1) * 64 + (lane & 7) * 8;
    const int c0 = (wave & 1) * 64 + (lane >> 3) * 8;
    float acc[8][8] = {};
    const float4* W4 = (const float4*)W;

    for (int p = 0; p < 2; ++p) {
        if (p) __syncthreads();
        {   // stage W rows [64p, 64p+64)
            float4* Wl4 = (float4*)Wh;
            #pragma unroll
            for (int i = 0; i < 8; ++i)
                Wl4[tid + 256 * i] = W4[p * 2048 + tid + 256 * i];
        }
        {   // stage X^T (swizzled)
            #pragma unroll
            for (int i = 0; i < 8; ++i) {
                int fidx = tid + 256 * i;      // 0..2047
                int r    = fidx >> 4;          // 0..127
                int k4l  = fidx & 15;          // 0..15 (local float4-group of k)
                int row  = row0 + r;
                float4 v = make_float4(0.f, 0.f, 0.f, 0.f);
                if (row < nrows) v = ld4(&A[(size_t)row * 128 + (p * 16 + k4l) * 4]);
                int rx = r ^ ((k4l & 7) << 2);
                Xt[(k4l * 4 + 0) * 128 + rx] = v.x;
                Xt[(k4l * 4 + 1) * 128 + rx] = v.y;
                Xt[(k4l * 4 + 2) * 128 + rx] = v.z;
                Xt[(k4l * 4 + 3) * 128 + rx] = v.w;
            }
        }
        __syncthreads();
        #pragma unroll 4
        for (int kk = 0; kk < 64; ++kk) {
            int sw = ((kk >> 2) & 7) << 2;
            float4 xa = ld4(&Xt[kk * 128 + (r0 ^ sw)]);
            float4 xb = ld4(&Xt[kk * 128 + ((r0 + 4) ^ sw)]);
            float4 wa = ld4(&Wh[kk * 128 + c0]);
            float4 wb = ld4(&Wh[kk * 128 + c0 + 4]);
            float xr[8] = {xa.x, xa.y, xa.z, xa.w, xb.x, xb.y, xb.z, xb.w};
            float wc[8] = {wa.x, wa.y, wa.z, wa.w, wb.x, wb.y, wb.z, wb.w};
            #pragma unroll
            for (int rr = 0; rr < 8; ++rr)
                #pragma unroll
                for (int cc = 0; cc < 8; ++cc)
                    acc[rr][cc] += xr[rr] * wc[cc];
        }
    }
    #pragma unroll
    for (int rr = 0; rr < 8; ++rr) {
        int row = row0 + r0 + rr;
        if (row < nrows) {
            float4 o0 = make_float4(acc[rr][0], acc[rr][1], acc[rr][2], acc[rr][3]);
            float4 o1 = make_float4(acc[rr][4], acc[rr][5], acc[rr][6], acc[rr][7]);
            *(float4*)&C[(size_t)row * 128 + c0]     = o0;
            *(float4*)&C[(size_t)row * 128 + c0 + 4] = o1;
        }
    }
}

// ---------------- gather-aggregate (fused self-loop + bias + relu) ----------------
__global__ __launch_bounds__(256) void k_gather(const float* __restrict__ h,
                                                const int* __restrict__ rs,
                                                const int* __restrict__ csrc,
                                                const float* __restrict__ cw,
                                                const float* __restrict__ dinv,
                                                const float* __restrict__ bias,
                                                float* __restrict__ out, int N) {
    int node = blockIdx.x * 8 + (threadIdx.x >> 5);
    if (node >= N) return;
    int f4i = threadIdx.x & 31;
    int p = rs[node], end = rs[node + 1];
    float ax = 0.f, ay = 0.f, az = 0.f, aw = 0.f;
    for (; p + 1 < end; p += 2) {
        int s0 = csrc[p];
        int s1 = csrc[p + 1];
        float n0 = cw[p], n1 = cw[p + 1];
        float4 v0 = ld4(&h[(size_t)s0 * 128 + f4i * 4]);
        float4 v1 = ld4(&h[(size_t)s1 * 128 + f4i * 4]);
        ax += n0 * v0.x + n1 * v1.x;
        ay += n0 * v0.y + n1 * v1.y;
        az += n0 * v0.z + n1 * v1.z;
        aw += n0 * v0.w + n1 * v1.w;
    }
    if (p < end) {
        int s0 = csrc[p];
        float n0 = cw[p];
        float4 v0 = ld4(&h[(size_t)s0 * 128 + f4i * 4]);
        ax += n0 * v0.x; ay += n0 * v0.y; az += n0 * v0.z; aw += n0 * v0.w;
    }
    float di = dinv[node];
    float sn = di * di;
    float4 hv = ld4(&h[(size_t)node * 128 + f4i * 4]);
    float4 bv = ld4(&bias[f4i * 4]);
    float4 o;
    o.x = fmaxf(ax + sn * hv.x + bv.x, 0.f);
    o.y = fmaxf(ay + sn * hv.y + bv.y, 0.f);
    o.z = fmaxf(az + sn * hv.z + bv.z, 0.f);
    o.w = fmaxf(aw + sn * hv.w + bv.w, 0.f);
    *(float4*)&out[(size_t)node * 128 + f4i * 4] = o;
}

// ---------------- segment-sum pool (batch sorted: flush on change) ----------------
__global__ __launch_bounds__(256) void k_pool(const float* __restrict__ h,
                                              const int* __restrict__ batch,
                                              float* __restrict__ out, int N) {
    int f4i = threadIdx.x & 31;
    int ln  = threadIdx.x >> 5;
    int base = blockIdx.x * 256;
    int end  = min(base + 256, N);
    float sx = 0.f, sy = 0.f, sz = 0.f, sw = 0.f;
    int cur = -1;
    for (int n = base + ln; n < end; n += 8) {
        int g = batch[n];
        if (g != cur) {
            if (cur >= 0) {
                float* op = &out[cur * 128 + f4i * 4];
                atomicAdd(op + 0, sx); atomicAdd(op + 1, sy);
                atomicAdd(op + 2, sz); atomicAdd(op + 3, sw);
            }
            cur = g; sx = sy = sz = sw = 0.f;
        }
        float4 v = ld4(&h[(size_t)n * 128 + f4i * 4]);
        sx += v.x; sy += v.y; sz += v.z; sw += v.w;
    }
    if (cur >= 0) {
        float* op = &out[cur * 128 + f4i * 4];
        atomicAdd(op + 0, sx); atomicAdd(op + 1, sy);
        atomicAdd(op + 2, sz); atomicAdd(op + 3, sw);
    }
}

extern "C" void kernel_launch(void* const* d_in, const int* in_sizes, int n_in,
                              void* d_out, int out_size, void* d_ws, size_t ws_size,
                              hipStream_t stream) {
    const float* x   = (const float*)d_in[0];
    const int*   ei  = (const int*)d_in[1];
    const float* ew  = (const float*)d_in[2];
    const int*  batch= (const int*)d_in[3];
    const float* W1  = (const float*)d_in[4];
    const float* b1  = (const float*)d_in[5];
    const float* W2  = (const float*)d_in[6];
    const float* b2  = (const float*)d_in[7];
    const int E = in_sizes[2];
    const int N = in_sizes[3];
    const int* srcp = ei;
    const int* dstp = ei + E;

    char* wsb = (char*)d_ws;
    size_t off = 0;
    auto alloc = [&](size_t bytes) -> void* {
        void* p = wsb + off;
        off += (bytes + 255) & ~(size_t)255;
        return p;
    };
    float* bufA = (float*)alloc((size_t)N * 128 * 4);  // 51.2 MB  (h = GEMM out)
    float* bufB = (float*)alloc((size_t)N * 128 * 4);  // 51.2 MB  (layer out)
    float* dinv = (float*)alloc((size_t)N * 4);
    int*   cnt  = (int*)alloc((size_t)N * 4);
    int*   rs   = (int*)alloc((size_t)(N + 1) * 4);
    int*   cur  = (int*)alloc((size_t)N * 4);
    int*   bsum = (int*)alloc(4096);
    int*   csrc = (int*)alloc((size_t)E * 4);          // 6.4 MB
    float* cw   = (float*)alloc((size_t)E * 4);        // 6.4 MB

    const int nbScan = (N + 1023) / 1024;

    hipMemsetAsync(dinv, 0, (size_t)N * 4, stream);
    hipMemsetAsync(cnt,  0, (size_t)N * 4, stream);
    k_hist <<<(E + 255) / 256, 256, 0, stream>>>(dstp, ew, dinv, cnt, E);
    k_dinv <<<(N + 255) / 256, 256, 0, stream>>>(dinv, N);
    k_scan1<<<nbScan, 256, 0, stream>>>(cnt, rs, bsum, N);
    k_scan2<<<1, 64, 0, stream>>>(bsum, nbScan);
    k_scan3<<<(N + 255) / 256, 256, 0, stream>>>(rs, cur, bsum, N, E);
    k_fill <<<(E + 255) / 256, 256, 0, stream>>>(srcp, dstp, ew, dinv, cur, csrc, cw, E);

    k_gemm  <<<(N + 127) / 128, 256, 0, stream>>>(x, W1, bufA, N);
    k_gather<<<(N + 7) / 8, 256, 0, stream>>>(bufA, rs, csrc, cw, dinv, b1, bufB, N);
    k_gemm  <<<(N + 127) / 128, 256, 0, stream>>>(bufB, W2, bufA, N);
    k_gather<<<(N + 7) / 8, 256, 0, stream>>>(bufA, rs, csrc, cw, dinv, b2, bufB, N);

    hipMemsetAsync(d_out, 0, (size_t)out_size * 4, stream);
    k_pool <<<(N + 255) / 256, 256, 0, stream>>>(bufB, batch, (float*)d_out, N);
}

// Round 2
// 623.759 us; speedup vs baseline: 1.1712x; 1.1712x over previous
//
#include <hip/hip_runtime.h>
#include <hip/hip_bf16.h>

// GCN 2-layer: packed hist (1 atomic/edge) -> dinv -> scan -> atomic-free fill
// -> [GEMM -> gather(+self+bias+relu)] x2 -> pool
// N = 100000, E = 1600000, F = 128, G = 64

__device__ __forceinline__ float4 ld4(const float* p) { return *(const float4*)p; }

#define DEG_MASK ((1ULL << 40) - 1ULL)

// ---------------- packed degree+count histogram ----------------
// pack[d]: bits[0,40) = sum(w * 2^32) fixed-point, bits[40,64) = edge count.
// Returned old value gives this edge's position within its dst bucket.
__global__ __launch_bounds__(256) void k_hist(const int* __restrict__ dst,
                                              const float* __restrict__ w,
                                              unsigned long long* __restrict__ pack,
                                              int* __restrict__ posInNode, int E) {
    int e = blockIdx.x * 256 + threadIdx.x;
    if (e >= E) return;
    int d = dst[e];
    unsigned long long add =
        (1ULL << 40) | (unsigned long long)(w[e] * 4294967296.0f);
    unsigned long long old = atomicAdd(&pack[d], add);
    posInNode[e] = (int)(old >> 40);
}

__global__ __launch_bounds__(256) void k_dinv(const unsigned long long* __restrict__ pack,
                                              float* __restrict__ dinv, int N) {
    int i = blockIdx.x * 256 + threadIdx.x;
    if (i < N) {
        double deg = (double)(pack[i] & DEG_MASK) * 0x1p-32 + 1.0;  // +1 self-loop
        dinv[i] = rsqrtf((float)deg);
    }
}

// ---------------- exclusive scan over counts (two-level) ----------------
__global__ __launch_bounds__(256) void k_scan1(const unsigned long long* __restrict__ pack,
                                               int* __restrict__ rs,
                                               int* __restrict__ bsum, int N) {
    __shared__ int wsum[4];
    int tid = threadIdx.x;
    int base = blockIdx.x * 1024 + tid * 4;
    int v0 = 0, v1 = 0, v2 = 0, v3 = 0;
    if (base + 0 < N) v0 = (int)(pack[base + 0] >> 40);
    if (base + 1 < N) v1 = (int)(pack[base + 1] >> 40);
    if (base + 2 < N) v2 = (int)(pack[base + 2] >> 40);
    if (base + 3 < N) v3 = (int)(pack[base + 3] >> 40);
    int ts = v0 + v1 + v2 + v3;
    int lane = tid & 63;
    int x = ts;
    #pragma unroll
    for (int off = 1; off < 64; off <<= 1) {
        int y = __shfl_up(x, off);
        if (lane >= off) x += y;
    }
    int wid = tid >> 6;
    if (lane == 63) wsum[wid] = x;
    __syncthreads();
    int woff = 0;
    for (int wI = 0; wI < wid; ++wI) woff += wsum[wI];
    int start = woff + x - ts;
    int o0 = start, o1 = start + v0, o2 = start + v0 + v1, o3 = start + v0 + v1 + v2;
    if (base + 3 < N) {
        *(int4*)&rs[base] = make_int4(o0, o1, o2, o3);
    } else {
        if (base + 0 < N) rs[base + 0] = o0;
        if (base + 1 < N) rs[base + 1] = o1;
        if (base + 2 < N) rs[base + 2] = o2;
        if (base + 3 < N) rs[base + 3] = o3;
    }
    if (tid == 255) bsum[blockIdx.x] = woff + x;
}

__global__ void k_scan2(int* bsum, int nb) {   // single wave
    int lane = threadIdx.x;
    int carry = 0;
    for (int b = 0; b < nb; b += 64) {
        int i = b + lane;
        int v = (i < nb) ? bsum[i] : 0;
        int x = v;
        #pragma unroll
        for (int off = 1; off < 64; off <<= 1) {
            int y = __shfl_up(x, off);
            if (lane >= off) x += y;
        }
        int tot = __shfl(x, 63);
        if (i < nb) bsum[i] = carry + x - v;
        carry += tot;
    }
}

__global__ __launch_bounds__(256) void k_scan3(int* __restrict__ rs,
                                               const int* __restrict__ bsum, int N, int E) {
    int i = blockIdx.x * 256 + threadIdx.x;
    if (i < N) rs[i] = rs[i] + bsum[i >> 10];
    if (i == 0) rs[N] = E;
}

// ---------------- CSR fill: atomic-free, packed (src, norm) pair ----------------
__global__ __launch_bounds__(256) void k_fill(const int* __restrict__ src,
                                              const int* __restrict__ dst,
                                              const float* __restrict__ w,
                                              const float* __restrict__ dinv,
                                              const int* __restrict__ rs,
                                              const int* __restrict__ posInNode,
                                              int2* __restrict__ pairs, int E) {
    int e = blockIdx.x * 256 + threadIdx.x;
    if (e >= E) return;
    int s = src[e], d = dst[e];
    int pos = rs[d] + posInNode[e];
    int2 pr;
    pr.x = s;
    pr.y = __float_as_int(dinv[s] * w[e] * dinv[d]);
    pairs[pos] = pr;
}

// ---------------- GEMM: C[N,128] = A[N,128] @ W[128,128] ----------------
__global__ __launch_bounds__(256, 1) void k_gemm(const float* __restrict__ A,
                                                 const float* __restrict__ W,
                                                 float* __restrict__ C, int nrows) {
    __shared__ float Wh[64 * 128];   // 32 KB
    __shared__ float Xt[64 * 128];   // 32 KB
    const int tid = threadIdx.x;
    const int row0 = blockIdx.x * 128;
    const int wave = tid >> 6, lane = tid & 63;
    const int r0 = (wave >> 1) * 64 + (lane & 7) * 8;
    const int c0 = (wave & 1) * 64 + (lane >> 3) * 8;
    float acc[8][8] = {};
    const float4* W4 = (const float4*)W;

    for (int p = 0; p < 2; ++p) {
        if (p) __syncthreads();
        {   // stage W rows
            float4* Wl4 = (float4*)Wh;
            #pragma unroll
            for (int i = 0; i < 8; ++i)
                Wl4[tid + 256 * i] = W4[p * 2048 + tid + 256 * i];
        }
        {   // stage X^T (swizzled)
            #pragma unroll
            for (int i = 0; i < 8; ++i) {
                int fidx = tid + 256 * i;
                int r    = fidx >> 4;
                int k4l  = fidx & 15;
                int row  = row0 + r;
                float4 v = make_float4(0.f, 0.f, 0.f, 0.f);
                if (row < nrows) v = ld4(&A[(size_t)row * 128 + (p * 16 + k4l) * 4]);
                int rx = r ^ ((k4l & 7) << 2);
                Xt[(k4l * 4 + 0) * 128 + rx] = v.x;
                Xt[(k4l * 4 + 1) * 128 + rx] = v.y;
                Xt[(k4l * 4 + 2) * 128 + rx] = v.z;
                Xt[(k4l * 4 + 3) * 128 + rx] = v.w;
            }
        }
        __syncthreads();
        #pragma unroll 4
        for (int kk = 0; kk < 64; ++kk) {
            int sw = ((kk >> 2) & 7) << 2;
            float4 xa = ld4(&Xt[kk * 128 + (r0 ^ sw)]);
            float4 xb = ld4(&Xt[kk * 128 + ((r0 + 4) ^ sw)]);
            float4 wa = ld4(&Wh[kk * 128 + c0]);
            float4 wb = ld4(&Wh[kk * 128 + c0 + 4]);
            float xr[8] = {xa.x, xa.y, xa.z, xa.w, xb.x, xb.y, xb.z, xb.w};
            float wc[8] = {wa.x, wa.y, wa.z, wa.w, wb.x, wb.y, wb.z, wb.w};
            #pragma unroll
            for (int rr = 0; rr < 8; ++rr)
                #pragma unroll
                for (int cc = 0; cc < 8; ++cc)
                    acc[rr][cc] += xr[rr] * wc[cc];
        }
    }
    #pragma unroll
    for (int rr = 0; rr < 8; ++rr) {
        int row = row0 + r0 + rr;
        if (row < nrows) {
            float4 o0 = make_float4(acc[rr][0], acc[rr][1], acc[rr][2], acc[rr][3]);
            float4 o1 = make_float4(acc[rr][4], acc[rr][5], acc[rr][6], acc[rr][7]);
            *(float4*)&C[(size_t)row * 128 + c0]     = o0;
            *(float4*)&C[(size_t)row * 128 + c0 + 4] = o1;
        }
    }
}

// ---------------- gather-aggregate: 1 wave per node, float2 per lane ----------------
__global__ __launch_bounds__(256) void k_gather(const float* __restrict__ h,
                                                const int* __restrict__ rs,
                                                const int2* __restrict__ pairs,
                                                const float* __restrict__ dinv,
                                                const float* __restrict__ bias,
                                                float* __restrict__ out, int N) {
    int node = blockIdx.x * 4 + (threadIdx.x >> 6);
    if (node >= N) return;
    int f2 = threadIdx.x & 63;          // float pair index 0..63
    int p = rs[node], end = rs[node + 1];
    float ax = 0.f, ay = 0.f;
    for (; p + 1 < end; p += 2) {
        int2 a = pairs[p];
        int2 b = pairs[p + 1];
        float wa = __int_as_float(a.y), wb = __int_as_float(b.y);
        float2 va = *(const float2*)&h[(size_t)a.x * 128 + f2 * 2];
        float2 vb = *(const float2*)&h[(size_t)b.x * 128 + f2 * 2];
        ax += wa * va.x + wb * vb.x;
        ay += wa * va.y + wb * vb.y;
    }
    if (p < end) {
        int2 a = pairs[p];
        float wa = __int_as_float(a.y);
        float2 va = *(const float2*)&h[(size_t)a.x * 128 + f2 * 2];
        ax += wa * va.x;
        ay += wa * va.y;
    }
    float di = dinv[node];
    float sn = di * di;
    float2 hv = *(const float2*)&h[(size_t)node * 128 + f2 * 2];
    float2 bv = *(const float2*)&bias[f2 * 2];
    float2 o;
    o.x = fmaxf(ax + sn * hv.x + bv.x, 0.f);
    o.y = fmaxf(ay + sn * hv.y + bv.y, 0.f);
    *(float2*)&out[(size_t)node * 128 + f2 * 2] = o;
}

// ---------------- segment-sum pool (batch sorted: flush on change) ----------------
__global__ __launch_bounds__(256) void k_pool(const float* __restrict__ h,
                                              const int* __restrict__ batch,
                                              float* __restrict__ out, int N) {
    int f4i = threadIdx.x & 31;
    int ln  = threadIdx.x >> 5;
    int base = blockIdx.x * 256;
    int end  = min(base + 256, N);
    float sx = 0.f, sy = 0.f, sz = 0.f, sw = 0.f;
    int cur = -1;
    for (int n = base + ln; n < end; n += 8) {
        int g = batch[n];
        if (g != cur) {
            if (cur >= 0) {
                float* op = &out[cur * 128 + f4i * 4];
                atomicAdd(op + 0, sx); atomicAdd(op + 1, sy);
                atomicAdd(op + 2, sz); atomicAdd(op + 3, sw);
            }
            cur = g; sx = sy = sz = sw = 0.f;
        }
        float4 v = ld4(&h[(size_t)n * 128 + f4i * 4]);
        sx += v.x; sy += v.y; sz += v.z; sw += v.w;
    }
    if (cur >= 0) {
        float* op = &out[cur * 128 + f4i * 4];
        atomicAdd(op + 0, sx); atomicAdd(op + 1, sy);
        atomicAdd(op + 2, sz); atomicAdd(op + 3, sw);
    }
}

extern "C" void kernel_launch(void* const* d_in, const int* in_sizes, int n_in,
                              void* d_out, int out_size, void* d_ws, size_t ws_size,
                              hipStream_t stream) {
    const float* x   = (const float*)d_in[0];
    const int*   ei  = (const int*)d_in[1];
    const float* ew  = (const float*)d_in[2];
    const int*  batch= (const int*)d_in[3];
    const float* W1  = (const float*)d_in[4];
    const float* b1  = (const float*)d_in[5];
    const float* W2  = (const float*)d_in[6];
    const float* b2  = (const float*)d_in[7];
    const int E = in_sizes[2];
    const int N = in_sizes[3];
    const int* srcp = ei;
    const int* dstp = ei + E;

    char* wsb = (char*)d_ws;
    size_t off = 0;
    auto alloc = [&](size_t bytes) -> void* {
        void* p = wsb + off;
        off += (bytes + 255) & ~(size_t)255;
        return p;
    };
    int2*  pairs = (int2*)alloc((size_t)E * 8);          // 12.8 MB packed (src,norm)
    float* bufA  = (float*)alloc((size_t)N * 128 * 4);   // 51.2 MB (GEMM out)
    float* bufB  = (float*)alloc((size_t)N * 128 * 4);   // 51.2 MB (layer out)
    unsigned long long* pack = (unsigned long long*)alloc((size_t)N * 8);  // 0.8 MB
    float* dinv  = (float*)alloc((size_t)N * 4);
    int*   rs    = (int*)alloc((size_t)(N + 1) * 4);
    int*   bsum  = (int*)alloc(4096);
    // posInNode aliases bufA: dead before k_gemm writes bufA.
    int*   posInNode = (int*)bufA;

    const int nbScan = (N + 1023) / 1024;

    hipMemsetAsync(pack, 0, (size_t)N * 8, stream);
    k_hist <<<(E + 255) / 256, 256, 0, stream>>>(dstp, ew, pack, posInNode, E);
    k_dinv <<<(N + 255) / 256, 256, 0, stream>>>(pack, dinv, N);
    k_scan1<<<nbScan, 256, 0, stream>>>(pack, rs, bsum, N);
    k_scan2<<<1, 64, 0, stream>>>(bsum, nbScan);
    k_scan3<<<(N + 255) / 256, 256, 0, stream>>>(rs, bsum, N, E);
    k_fill <<<(E + 255) / 256, 256, 0, stream>>>(srcp, dstp, ew, dinv, rs, posInNode, pairs, E);

    k_gemm  <<<(N + 127) / 128, 256, 0, stream>>>(x, W1, bufA, N);
    k_gather<<<(N + 3) / 4, 256, 0, stream>>>(bufA, rs, pairs, dinv, b1, bufB, N);
    k_gemm  <<<(N + 127) / 128, 256, 0, stream>>>(bufB, W2, bufA, N);
    k_gather<<<(N + 3) / 4, 256, 0, stream>>>(bufA, rs, pairs, dinv, b2, bufB, N);

    hipMemsetAsync(d_out, 0, (size_t)out_size * 4, stream);
    k_pool <<<(N + 255) / 256, 256, 0, stream>>>(bufB, batch, (float*)d_out, N);
}

// Round 3
// 479.903 us; speedup vs baseline: 1.5223x; 1.2998x over previous
//
#include <hip/hip_runtime.h>
#include <hip/hip_bf16.h>

// GCN 2-layer, bf16 h + MFMA GEMM:
// hist(1 atomic/edge) -> dinv -> scan -> fill -> cvt(x,W) ->
// [MFMA-GEMM -> half-wave gather(+self+bias+relu)] x2 -> pool
// N = 100000, E = 1600000, F = 128, G = 64

typedef __attribute__((ext_vector_type(8))) short bf16x8;
typedef __attribute__((ext_vector_type(4))) float f32x4;

#define DEG_MASK ((1ULL << 40) - 1ULL)

__device__ __forceinline__ unsigned short f2b(float f) {   // fp32 -> bf16 RNE
    unsigned int u = __float_as_uint(f);
    return (unsigned short)((u + 0x7fffu + ((u >> 16) & 1u)) >> 16);
}
__device__ __forceinline__ float bflo(unsigned int u) { return __uint_as_float(u << 16); }
__device__ __forceinline__ float bfhi(unsigned int u) { return __uint_as_float(u & 0xffff0000u); }

// ---------------- packed degree+count histogram ----------------
__global__ __launch_bounds__(256) void k_hist(const int* __restrict__ dst,
                                              const float* __restrict__ w,
                                              unsigned long long* __restrict__ pack,
                                              int* __restrict__ posInNode, int E) {
    int e = blockIdx.x * 256 + threadIdx.x;
    if (e >= E) return;
    int d = dst[e];
    unsigned long long add =
        (1ULL << 40) | (unsigned long long)(w[e] * 4294967296.0f);
    unsigned long long old = atomicAdd(&pack[d], add);
    posInNode[e] = (int)(old >> 40);
}

__global__ __launch_bounds__(256) void k_dinv(const unsigned long long* __restrict__ pack,
                                              float* __restrict__ dinv, int N) {
    int i = blockIdx.x * 256 + threadIdx.x;
    if (i < N) {
        double deg = (double)(pack[i] & DEG_MASK) * 0x1p-32 + 1.0;  // +1 self-loop
        dinv[i] = rsqrtf((float)deg);
    }
}

// ---------------- exclusive scan over counts (two-level) ----------------
__global__ __launch_bounds__(256) void k_scan1(const unsigned long long* __restrict__ pack,
                                               int* __restrict__ rs,
                                               int* __restrict__ bsum, int N) {
    __shared__ int wsum[4];
    int tid = threadIdx.x;
    int base = blockIdx.x * 1024 + tid * 4;
    int v0 = 0, v1 = 0, v2 = 0, v3 = 0;
    if (base + 0 < N) v0 = (int)(pack[base + 0] >> 40);
    if (base + 1 < N) v1 = (int)(pack[base + 1] >> 40);
    if (base + 2 < N) v2 = (int)(pack[base + 2] >> 40);
    if (base + 3 < N) v3 = (int)(pack[base + 3] >> 40);
    int ts = v0 + v1 + v2 + v3;
    int lane = tid & 63;
    int x = ts;
    #pragma unroll
    for (int off = 1; off < 64; off <<= 1) {
        int y = __shfl_up(x, off);
        if (lane >= off) x += y;
    }
    int wid = tid >> 6;
    if (lane == 63) wsum[wid] = x;
    __syncthreads();
    int woff = 0;
    for (int wI = 0; wI < wid; ++wI) woff += wsum[wI];
    int start = woff + x - ts;
    int o0 = start, o1 = start + v0, o2 = start + v0 + v1, o3 = start + v0 + v1 + v2;
    if (base + 3 < N) {
        *(int4*)&rs[base] = make_int4(o0, o1, o2, o3);
    } else {
        if (base + 0 < N) rs[base + 0] = o0;
        if (base + 1 < N) rs[base + 1] = o1;
        if (base + 2 < N) rs[base + 2] = o2;
        if (base + 3 < N) rs[base + 3] = o3;
    }
    if (tid == 255) bsum[blockIdx.x] = woff + x;
}

__global__ void k_scan2(int* bsum, int nb) {   // single wave
    int lane = threadIdx.x;
    int carry = 0;
    for (int b = 0; b < nb; b += 64) {
        int i = b + lane;
        int v = (i < nb) ? bsum[i] : 0;
        int x = v;
        #pragma unroll
        for (int off = 1; off < 64; off <<= 1) {
            int y = __shfl_up(x, off);
            if (lane >= off) x += y;
        }
        int tot = __shfl(x, 63);
        if (i < nb) bsum[i] = carry + x - v;
        carry += tot;
    }
}

__global__ __launch_bounds__(256) void k_scan3(int* __restrict__ rs,
                                               const int* __restrict__ bsum, int N, int E) {
    int i = blockIdx.x * 256 + threadIdx.x;
    if (i < N) rs[i] = rs[i] + bsum[i >> 10];
    if (i == 0) rs[N] = E;
}

// ---------------- CSR fill: atomic-free, packed (src, norm) pair ----------------
__global__ __launch_bounds__(256) void k_fill(const int* __restrict__ src,
                                              const int* __restrict__ dst,
                                              const float* __restrict__ w,
                                              const float* __restrict__ dinv,
                                              const int* __restrict__ rs,
                                              const int* __restrict__ posInNode,
                                              int2* __restrict__ pairs, int E) {
    int e = blockIdx.x * 256 + threadIdx.x;
    if (e >= E) return;
    int s = src[e], d = dst[e];
    int pos = rs[d] + posInNode[e];
    int2 pr;
    pr.x = s;
    pr.y = __float_as_int(dinv[s] * w[e] * dinv[d]);
    pairs[pos] = pr;
}

// ---------------- converts ----------------
__global__ __launch_bounds__(256) void k_cvt_x(const float* __restrict__ in,
                                               unsigned short* __restrict__ o, int n4) {
    int i = blockIdx.x * 256 + threadIdx.x;
    if (i >= n4) return;
    float4 v = *(const float4*)&in[(size_t)i * 4];
    uint2 r;
    r.x = (unsigned int)f2b(v.x) | ((unsigned int)f2b(v.y) << 16);
    r.y = (unsigned int)f2b(v.z) | ((unsigned int)f2b(v.w) << 16);
    *(uint2*)&o[(size_t)i * 4] = r;
}

// W[128k][128n] fp32 -> Wt[128n][128k] bf16
__global__ __launch_bounds__(256) void k_cvt_wT(const float* __restrict__ W,
                                                unsigned short* __restrict__ Wt) {
    int idx = blockIdx.x * 256 + threadIdx.x;   // 16384
    int k = idx >> 7, n = idx & 127;
    Wt[n * 128 + k] = f2b(W[idx]);
}

// ---------------- MFMA GEMM: C[N,128]bf16 = A[N,128]bf16 @ W ----------------
// Wt is [n][k] bf16. One block = 128 rows, 4 waves x 32 rows. K=128 in regs.
__global__ __launch_bounds__(256) void k_gemm(const unsigned short* __restrict__ A,
                                              const unsigned short* __restrict__ Wt,
                                              unsigned short* __restrict__ C, int nrows) {
    __shared__ unsigned int Wl[8192];   // 32 KB, swizzled: byte = n*256 + (koff ^ ((n&7)<<4))
    const int tid = threadIdx.x;
    const int row0 = blockIdx.x * 128;
    {   // stage Wt (coalesced read, swizzled write)
        const unsigned int* Wg = (const unsigned int*)Wt;
        #pragma unroll
        for (int i = 0; i < 32; ++i) {
            int u = tid + 256 * i;
            int n = u >> 6, kp = u & 63;
            unsigned int val = Wg[u];
            *(unsigned int*)((char*)Wl + n * 256 + ((kp * 4) ^ ((n & 7) << 4))) = val;
        }
    }
    const int lane = tid & 63, wv = tid >> 6;
    const int m0 = row0 + wv * 32;
    const int lr = lane & 15, lg = lane >> 4;

    bf16x8 a[2][4];
    #pragma unroll
    for (int mi = 0; mi < 2; ++mi)
        #pragma unroll
        for (int kb = 0; kb < 4; ++kb) {
            int r = m0 + mi * 16 + lr;
            if (r < nrows)
                a[mi][kb] = *(const bf16x8*)&A[(size_t)r * 128 + kb * 32 + lg * 8];
            else
                a[mi][kb] = (bf16x8)0;
        }
    __syncthreads();

    f32x4 acc[2][8] = {};
    #pragma unroll
    for (int nb = 0; nb < 8; ++nb) {
        #pragma unroll
        for (int kb = 0; kb < 4; ++kb) {
            int n = nb * 16 + lr;
            int koff = kb * 64 + lg * 16;
            bf16x8 b = *(const bf16x8*)((const char*)Wl + n * 256 + (koff ^ ((n & 7) << 4)));
            acc[0][nb] = __builtin_amdgcn_mfma_f32_16x16x32_bf16(a[0][kb], b, acc[0][nb], 0, 0, 0);
            acc[1][nb] = __builtin_amdgcn_mfma_f32_16x16x32_bf16(a[1][kb], b, acc[1][nb], 0, 0, 0);
        }
    }
    // C/D: col = lane&15, row = (lane>>4)*4 + reg
    #pragma unroll
    for (int mi = 0; mi < 2; ++mi) {
        int rbase = m0 + mi * 16 + lg * 4;
        #pragma unroll
        for (int nb = 0; nb < 8; ++nb) {
            int col = nb * 16 + lr;
            #pragma unroll
            for (int r = 0; r < 4; ++r) {
                int row = rbase + r;
                if (row < nrows) C[(size_t)row * 128 + col] = f2b(acc[mi][nb][r]);
            }
        }
    }
}

// ---------------- gather: 1 wave/node, half-wave per edge, bf16 rows ----------------
__global__ __launch_bounds__(256) void k_gather(const unsigned short* __restrict__ h,
                                                const int* __restrict__ rs,
                                                const int2* __restrict__ pairs,
                                                const float* __restrict__ dinv,
                                                const float* __restrict__ bias,
                                                unsigned short* __restrict__ out, int N) {
    int node = blockIdx.x * 4 + (threadIdx.x >> 6);
    if (node >= N) return;
    int lane = threadIdx.x & 63;
    int half = lane >> 5;        // 0: edge a, 1: edge b
    int fl = lane & 31;          // feature quad: features 4*fl .. 4*fl+3
    const char* hb = (const char*)h;
    int p = rs[node], end = rs[node + 1];
    float a0 = 0.f, a1 = 0.f, a2 = 0.f, a3 = 0.f;
    for (; p + 1 < end; p += 2) {
        int2 pr = pairs[p + half];
        float w = __int_as_float(pr.y);
        uint2 v = *(const uint2*)(hb + (size_t)pr.x * 256 + fl * 8);
        a0 += w * bflo(v.x); a1 += w * bfhi(v.x);
        a2 += w * bflo(v.y); a3 += w * bfhi(v.y);
    }
    if (p < end) {   // odd tail: both halves read edge p, high half contributes 0
        int2 pr = pairs[p];
        float w = half ? 0.f : __int_as_float(pr.y);
        uint2 v = *(const uint2*)(hb + (size_t)pr.x * 256 + fl * 8);
        a0 += w * bflo(v.x); a1 += w * bfhi(v.x);
        a2 += w * bflo(v.y); a3 += w * bfhi(v.y);
    }
    a0 += __shfl_xor(a0, 32);
    a1 += __shfl_xor(a1, 32);
    a2 += __shfl_xor(a2, 32);
    a3 += __shfl_xor(a3, 32);
    float di = dinv[node];
    float sn = di * di;
    uint2 sv = *(const uint2*)(hb + (size_t)node * 256 + fl * 8);
    float4 bv = *(const float4*)&bias[fl * 4];
    float o0 = fmaxf(a0 + sn * bflo(sv.x) + bv.x, 0.f);
    float o1 = fmaxf(a1 + sn * bfhi(sv.x) + bv.y, 0.f);
    float o2 = fmaxf(a2 + sn * bflo(sv.y) + bv.z, 0.f);
    float o3 = fmaxf(a3 + sn * bfhi(sv.y) + bv.w, 0.f);
    if (half == 0) {
        uint2 ov;
        ov.x = (unsigned int)f2b(o0) | ((unsigned int)f2b(o1) << 16);
        ov.y = (unsigned int)f2b(o2) | ((unsigned int)f2b(o3) << 16);
        *(uint2*)((char*)out + (size_t)node * 256 + fl * 8) = ov;
    }
}

// ---------------- segment-sum pool (batch sorted: flush on change) ----------------
__global__ __launch_bounds__(256) void k_pool(const unsigned short* __restrict__ h,
                                              const int* __restrict__ batch,
                                              float* __restrict__ out, int N) {
    int f4i = threadIdx.x & 31;
    int ln  = threadIdx.x >> 5;
    int base = blockIdx.x * 256;
    int end  = min(base + 256, N);
    const char* hb = (const char*)h;
    float sx = 0.f, sy = 0.f, sz = 0.f, sw = 0.f;
    int cur = -1;
    for (int n = base + ln; n < end; n += 8) {
        int g = batch[n];
        if (g != cur) {
            if (cur >= 0) {
                float* op = &out[cur * 128 + f4i * 4];
                atomicAdd(op + 0, sx); atomicAdd(op + 1, sy);
                atomicAdd(op + 2, sz); atomicAdd(op + 3, sw);
            }
            cur = g; sx = sy = sz = sw = 0.f;
        }
        uint2 v = *(const uint2*)(hb + (size_t)n * 256 + f4i * 8);
        sx += bflo(v.x); sy += bfhi(v.x);
        sz += bflo(v.y); sw += bfhi(v.y);
    }
    if (cur >= 0) {
        float* op = &out[cur * 128 + f4i * 4];
        atomicAdd(op + 0, sx); atomicAdd(op + 1, sy);
        atomicAdd(op + 2, sz); atomicAdd(op + 3, sw);
    }
}

extern "C" void kernel_launch(void* const* d_in, const int* in_sizes, int n_in,
                              void* d_out, int out_size, void* d_ws, size_t ws_size,
                              hipStream_t stream) {
    const float* x   = (const float*)d_in[0];
    const int*   ei  = (const int*)d_in[1];
    const float* ew  = (const float*)d_in[2];
    const int*  batch= (const int*)d_in[3];
    const float* W1  = (const float*)d_in[4];
    const float* b1  = (const float*)d_in[5];
    const float* W2  = (const float*)d_in[6];
    const float* b2  = (const float*)d_in[7];
    const int E = in_sizes[2];
    const int N = in_sizes[3];
    const int* srcp = ei;
    const int* dstp = ei + E;

    char* wsb = (char*)d_ws;
    size_t off = 0;
    auto alloc = [&](size_t bytes) -> void* {
        void* p = wsb + off;
        off += (bytes + 255) & ~(size_t)255;
        return p;
    };
    int2*  pairs = (int2*)alloc((size_t)E * 8);                     // 12.8 MB
    unsigned short* xb = (unsigned short*)alloc((size_t)N * 128 * 2);  // 25.6 MB
    unsigned short* hA = (unsigned short*)alloc((size_t)N * 128 * 2);  // 25.6 MB
    unsigned short* hB = (unsigned short*)alloc((size_t)N * 128 * 2);  // 25.6 MB
    unsigned long long* pack = (unsigned long long*)alloc((size_t)N * 8);
    float* dinv  = (float*)alloc((size_t)N * 4);
    int*   rs    = (int*)alloc((size_t)(N + 1) * 4);
    int*   bsum  = (int*)alloc(4096);
    unsigned short* W1t = (unsigned short*)alloc(128 * 128 * 2);
    unsigned short* W2t = (unsigned short*)alloc(128 * 128 * 2);
    // posInNode aliases xb: written by k_hist, read by k_fill, then k_cvt_x overwrites.
    int* posInNode = (int*)xb;

    const int nbScan = (N + 1023) / 1024;

    hipMemsetAsync(pack, 0, (size_t)N * 8, stream);
    k_hist <<<(E + 255) / 256, 256, 0, stream>>>(dstp, ew, pack, posInNode, E);
    k_dinv <<<(N + 255) / 256, 256, 0, stream>>>(pack, dinv, N);
    k_scan1<<<nbScan, 256, 0, stream>>>(pack, rs, bsum, N);
    k_scan2<<<1, 64, 0, stream>>>(bsum, nbScan);
    k_scan3<<<(N + 255) / 256, 256, 0, stream>>>(rs, bsum, N, E);
    k_fill <<<(E + 255) / 256, 256, 0, stream>>>(srcp, dstp, ew, dinv, rs, posInNode, pairs, E);

    k_cvt_x <<<(N * 128 / 4 + 255) / 256, 256, 0, stream>>>(x, xb, N * 128 / 4);
    k_cvt_wT<<<64, 256, 0, stream>>>(W1, W1t);
    k_cvt_wT<<<64, 256, 0, stream>>>(W2, W2t);

    k_gemm  <<<(N + 127) / 128, 256, 0, stream>>>(xb, W1t, hA, N);
    k_gather<<<(N + 3) / 4, 256, 0, stream>>>(hA, rs, pairs, dinv, b1, hB, N);
    k_gemm  <<<(N + 127) / 128, 256, 0, stream>>>(hB, W2t, hA, N);
    k_gather<<<(N + 3) / 4, 256, 0, stream>>>(hA, rs, pairs, dinv, b2, hB, N);

    hipMemsetAsync(d_out, 0, (size_t)out_size * 4, stream);
    k_pool <<<(N + 255) / 256, 256, 0, stream>>>(hB, batch, (float*)d_out, N);
}

// Round 4
// 409.601 us; speedup vs baseline: 1.7835x; 1.1716x over previous
//
#include <hip/hip_runtime.h>
#include <hip/hip_bf16.h>

// GCN 2-layer, bf16 h + MFMA GEMM, fused stages:
// memset -> front[hist(padded atomics) | cvt_x | cvt_W1 | cvt_W2] -> scan1(+dinv)
// -> scan2 -> scan3 -> [fill | gemm1] -> gather1 -> gemm2 -> gather2 -> pool
// N = 100000, E = 1600000, F = 128, G = 64

typedef __attribute__((ext_vector_type(8))) short bf16x8;
typedef __attribute__((ext_vector_type(4))) float f32x4;

#define DEG_MASK ((1ULL << 40) - 1ULL)
#define PSTRIDE 8   // u64 slots per node: 64B line per node to kill atomic line-collisions

__device__ __forceinline__ unsigned short f2b(float f) {   // fp32 -> bf16 RNE
    unsigned int u = __float_as_uint(f);
    return (unsigned short)((u + 0x7fffu + ((u >> 16) & 1u)) >> 16);
}
__device__ __forceinline__ float bflo(unsigned int u) { return __uint_as_float(u << 16); }
__device__ __forceinline__ float bfhi(unsigned int u) { return __uint_as_float(u & 0xffff0000u); }

// ---------------- fused front: hist | cvt_x | cvt_W ----------------
__global__ __launch_bounds__(256) void k_front(const int* __restrict__ dst,
                                               const float* __restrict__ w,
                                               unsigned long long* __restrict__ pack,
                                               int* __restrict__ posInNode, int E,
                                               const float* __restrict__ x,
                                               unsigned short* __restrict__ xb, int n4,
                                               const float* __restrict__ W1,
                                               unsigned short* __restrict__ W1t,
                                               const float* __restrict__ W2,
                                               unsigned short* __restrict__ W2t,
                                               int HB, int CB) {
    int b = blockIdx.x, tid = threadIdx.x;
    if (b < HB) {                       // histogram: 1 packed atomic per edge
        int e = b * 256 + tid;
        if (e < E) {
            int d = dst[e];
            unsigned long long add =
                (1ULL << 40) | (unsigned long long)(w[e] * 4294967296.0f);
            unsigned long long old = atomicAdd(&pack[(size_t)d * PSTRIDE], add);
            posInNode[e] = (int)(old >> 40);
        }
    } else if (b < HB + CB) {           // x fp32 -> bf16
        int i = (b - HB) * 256 + tid;
        if (i < n4) {
            float4 v = *(const float4*)&x[(size_t)i * 4];
            uint2 r;
            r.x = (unsigned int)f2b(v.x) | ((unsigned int)f2b(v.y) << 16);
            r.y = (unsigned int)f2b(v.z) | ((unsigned int)f2b(v.w) << 16);
            *(uint2*)&xb[(size_t)i * 4] = r;
        }
    } else {                            // W[128k][128n] fp32 -> Wt[128n][128k] bf16
        int wsel = b - HB - CB;         // 0..127
        const float* W = (wsel < 64) ? W1 : W2;
        unsigned short* Wt = (wsel < 64) ? W1t : W2t;
        int idx = (wsel & 63) * 256 + tid;
        int k = idx >> 7, n = idx & 127;
        Wt[n * 128 + k] = f2b(W[idx]);
    }
}

// ---------------- scan1 (+dinv fused) ----------------
__global__ __launch_bounds__(256) void k_scan1(const unsigned long long* __restrict__ pack,
                                               float* __restrict__ dinv,
                                               int* __restrict__ rs,
                                               int* __restrict__ bsum, int N) {
    __shared__ int wsum[4];
    int tid = threadIdx.x;
    int base = blockIdx.x * 1024 + tid * 4;
    int v0 = 0, v1 = 0, v2 = 0, v3 = 0;
    float d0 = 0.f, d1 = 0.f, d2 = 0.f, d3 = 0.f;
    unsigned long long p0 = 0, p1 = 0, p2 = 0, p3 = 0;
    if (base + 0 < N) p0 = pack[(size_t)(base + 0) * PSTRIDE];
    if (base + 1 < N) p1 = pack[(size_t)(base + 1) * PSTRIDE];
    if (base + 2 < N) p2 = pack[(size_t)(base + 2) * PSTRIDE];
    if (base + 3 < N) p3 = pack[(size_t)(base + 3) * PSTRIDE];
    v0 = (int)(p0 >> 40); v1 = (int)(p1 >> 40);
    v2 = (int)(p2 >> 40); v3 = (int)(p3 >> 40);
    d0 = rsqrtf((float)((double)(p0 & DEG_MASK) * 0x1p-32 + 1.0));
    d1 = rsqrtf((float)((double)(p1 & DEG_MASK) * 0x1p-32 + 1.0));
    d2 = rsqrtf((float)((double)(p2 & DEG_MASK) * 0x1p-32 + 1.0));
    d3 = rsqrtf((float)((double)(p3 & DEG_MASK) * 0x1p-32 + 1.0));
    if (base + 3 < N) {
        *(float4*)&dinv[base] = make_float4(d0, d1, d2, d3);
    } else {
        if (base + 0 < N) dinv[base + 0] = d0;
        if (base + 1 < N) dinv[base + 1] = d1;
        if (base + 2 < N) dinv[base + 2] = d2;
    }
    int ts = v0 + v1 + v2 + v3;
    int lane = tid & 63;
    int x = ts;
    #pragma unroll
    for (int off = 1; off < 64; off <<= 1) {
        int y = __shfl_up(x, off);
        if (lane >= off) x += y;
    }
    int wid = tid >> 6;
    if (lane == 63) wsum[wid] = x;
    __syncthreads();
    int woff = 0;
    for (int wI = 0; wI < wid; ++wI) woff += wsum[wI];
    int start = woff + x - ts;
    int o0 = start, o1 = start + v0, o2 = start + v0 + v1, o3 = start + v0 + v1 + v2;
    if (base + 3 < N) {
        *(int4*)&rs[base] = make_int4(o0, o1, o2, o3);
    } else {
        if (base + 0 < N) rs[base + 0] = o0;
        if (base + 1 < N) rs[base + 1] = o1;
        if (base + 2 < N) rs[base + 2] = o2;
        if (base + 3 < N) rs[base + 3] = o3;
    }
    if (tid == 255) bsum[blockIdx.x] = woff + x;
}

__global__ void k_scan2(int* bsum, int nb) {   // single wave
    int lane = threadIdx.x;
    int carry = 0;
    for (int b = 0; b < nb; b += 64) {
        int i = b + lane;
        int v = (i < nb) ? bsum[i] : 0;
        int x = v;
        #pragma unroll
        for (int off = 1; off < 64; off <<= 1) {
            int y = __shfl_up(x, off);
            if (lane >= off) x += y;
        }
        int tot = __shfl(x, 63);
        if (i < nb) bsum[i] = carry + x - v;
        carry += tot;
    }
}

__global__ __launch_bounds__(256) void k_scan3(int* __restrict__ rs,
                                               const int* __restrict__ bsum, int N, int E) {
    int i = blockIdx.x * 256 + threadIdx.x;
    if (i < N) rs[i] = rs[i] + bsum[i >> 10];
    if (i == 0) rs[N] = E;
}

// ---------------- GEMM body (shared by k_gemm and k_fill_gemm) ----------------
__device__ __forceinline__ void gemm_body(unsigned int* Wl,
                                          const unsigned short* __restrict__ A,
                                          const unsigned short* __restrict__ Wt,
                                          unsigned short* __restrict__ C,
                                          int nrows, int blk) {
    const int tid = threadIdx.x;
    const int row0 = blk * 128;
    {   // stage Wt (coalesced read, swizzled write): byte = n*256 + (koff ^ ((n&7)<<4))
        const unsigned int* Wg = (const unsigned int*)Wt;
        #pragma unroll
        for (int i = 0; i < 32; ++i) {
            int u = tid + 256 * i;
            int n = u >> 6, kp = u & 63;
            unsigned int val = Wg[u];
            *(unsigned int*)((char*)Wl + n * 256 + ((kp * 4) ^ ((n & 7) << 4))) = val;
        }
    }
    const int lane = tid & 63, wv = tid >> 6;
    const int m0 = row0 + wv * 32;
    const int lr = lane & 15, lg = lane >> 4;

    bf16x8 a[2][4];
    #pragma unroll
    for (int mi = 0; mi < 2; ++mi)
        #pragma unroll
        for (int kb = 0; kb < 4; ++kb) {
            int r = m0 + mi * 16 + lr;
            if (r < nrows)
                a[mi][kb] = *(const bf16x8*)&A[(size_t)r * 128 + kb * 32 + lg * 8];
            else
                a[mi][kb] = (bf16x8)0;
        }
    __syncthreads();

    f32x4 acc[2][8] = {};
    #pragma unroll
    for (int nb = 0; nb < 8; ++nb) {
        #pragma unroll
        for (int kb = 0; kb < 4; ++kb) {
            int n = nb * 16 + lr;
            int koff = kb * 64 + lg * 16;
            bf16x8 bfrag = *(const bf16x8*)((const char*)Wl + n * 256 + (koff ^ ((n & 7) << 4)));
            acc[0][nb] = __builtin_amdgcn_mfma_f32_16x16x32_bf16(a[0][kb], bfrag, acc[0][nb], 0, 0, 0);
            acc[1][nb] = __builtin_amdgcn_mfma_f32_16x16x32_bf16(a[1][kb], bfrag, acc[1][nb], 0, 0, 0);
        }
    }
    // C/D: col = lane&15, row = (lane>>4)*4 + reg
    #pragma unroll
    for (int mi = 0; mi < 2; ++mi) {
        int rbase = m0 + mi * 16 + lg * 4;
        #pragma unroll
        for (int nb = 0; nb < 8; ++nb) {
            int col = nb * 16 + lr;
            #pragma unroll
            for (int r = 0; r < 4; ++r) {
                int row = rbase + r;
                if (row < nrows) C[(size_t)row * 128 + col] = f2b(acc[mi][nb][r]);
            }
        }
    }
}

__global__ __launch_bounds__(256) void k_gemm(const unsigned short* __restrict__ A,
                                              const unsigned short* __restrict__ Wt,
                                              unsigned short* __restrict__ C, int nrows) {
    __shared__ unsigned int Wl[8192];
    gemm_body(Wl, A, Wt, C, nrows, blockIdx.x);
}

// ---------------- fused fill | gemm1 ----------------
__global__ __launch_bounds__(256) void k_fill_gemm(const int* __restrict__ src,
                                                   const int* __restrict__ dst,
                                                   const float* __restrict__ w,
                                                   const float* __restrict__ dinv,
                                                   const int* __restrict__ rs,
                                                   const int* __restrict__ posInNode,
                                                   int2* __restrict__ pairs, int E,
                                                   const unsigned short* __restrict__ A,
                                                   const unsigned short* __restrict__ Wt,
                                                   unsigned short* __restrict__ C,
                                                   int nrows, int FB) {
    __shared__ unsigned int Wl[8192];
    int b = blockIdx.x;
    if (b < FB) {    // CSR fill, atomic-free
        int e = b * 256 + threadIdx.x;
        if (e < E) {
            int s = src[e], d = dst[e];
            int pos = rs[d] + posInNode[e];
            int2 pr;
            pr.x = s;
            pr.y = __float_as_int(dinv[s] * w[e] * dinv[d]);
            pairs[pos] = pr;
        }
        return;
    }
    gemm_body(Wl, A, Wt, C, nrows, b - FB);
}

// ---------------- gather: 1 wave/node, 4 edge-groups x 16 lanes, 2x unroll ----------------
#define ACC8(v, wt)                                            \
    a0 += wt * bflo(v.x); a1 += wt * bfhi(v.x);                \
    a2 += wt * bflo(v.y); a3 += wt * bfhi(v.y);                \
    a4 += wt * bflo(v.z); a5 += wt * bfhi(v.z);                \
    a6 += wt * bflo(v.w); a7 += wt * bfhi(v.w);

__global__ __launch_bounds__(256) void k_gather(const unsigned short* __restrict__ h,
                                                const int* __restrict__ rs,
                                                const int2* __restrict__ pairs,
                                                const float* __restrict__ dinv,
                                                const float* __restrict__ bias,
                                                unsigned short* __restrict__ out, int N) {
    int node = blockIdx.x * 4 + (threadIdx.x >> 6);
    if (node >= N) return;
    int lane = threadIdx.x & 63;
    int g  = lane >> 4;          // edge group 0..3
    int fl = lane & 15;          // 16B segment of the 256B row
    const char* hb = (const char*)h;
    int p = rs[node], end = rs[node + 1];
    float a0 = 0.f, a1 = 0.f, a2 = 0.f, a3 = 0.f;
    float a4 = 0.f, a5 = 0.f, a6 = 0.f, a7 = 0.f;
    for (; p + 8 <= end; p += 8) {         // 8 edges/iter: 2 independent 1KB row-loads
        int2 prA = pairs[p + g];
        int2 prB = pairs[p + 4 + g];
        float wA = __int_as_float(prA.y);
        float wB = __int_as_float(prB.y);
        uint4 vA = *(const uint4*)(hb + (size_t)prA.x * 256 + fl * 16);
        uint4 vB = *(const uint4*)(hb + (size_t)prB.x * 256 + fl * 16);
        ACC8(vA, wA);
        ACC8(vB, wB);
    }
    if (p + 4 <= end) {
        int2 pr = pairs[p + g];
        float wt = __int_as_float(pr.y);
        uint4 v = *(const uint4*)(hb + (size_t)pr.x * 256 + fl * 16);
        ACC8(v, wt);
        p += 4;
    }
    int r = end - p;                       // 0..3 tail
    if (r > 0) {
        int idx = p + (g < r ? g : 0);
        int2 pr = pairs[idx];
        float wt = (g < r) ? __int_as_float(pr.y) : 0.f;
        uint4 v = *(const uint4*)(hb + (size_t)pr.x * 256 + fl * 16);
        ACC8(v, wt);
    }
    // reduce across the 4 groups
    a0 += __shfl_xor(a0, 16); a1 += __shfl_xor(a1, 16);
    a2 += __shfl_xor(a2, 16); a3 += __shfl_xor(a3, 16);
    a4 += __shfl_xor(a4, 16); a5 += __shfl_xor(a5, 16);
    a6 += __shfl_xor(a6, 16); a7 += __shfl_xor(a7, 16);
    a0 += __shfl_xor(a0, 32); a1 += __shfl_xor(a1, 32);
    a2 += __shfl_xor(a2, 32); a3 += __shfl_xor(a3, 32);
    a4 += __shfl_xor(a4, 32); a5 += __shfl_xor(a5, 32);
    a6 += __shfl_xor(a6, 32); a7 += __shfl_xor(a7, 32);
    if (g == 0) {   // epilogue: self-loop + bias + relu, store 16B
        float di = dinv[node];
        float sn = di * di;
        uint4 sv = *(const uint4*)(hb + (size_t)node * 256 + fl * 16);
        float4 b0 = *(const float4*)&bias[fl * 8];
        float4 b1 = *(const float4*)&bias[fl * 8 + 4];
        float o0 = fmaxf(a0 + sn * bflo(sv.x) + b0.x, 0.f);
        float o1 = fmaxf(a1 + sn * bfhi(sv.x) + b0.y, 0.f);
        float o2 = fmaxf(a2 + sn * bflo(sv.y) + b0.z, 0.f);
        float o3 = fmaxf(a3 + sn * bfhi(sv.y) + b0.w, 0.f);
        float o4 = fmaxf(a4 + sn * bflo(sv.z) + b1.x, 0.f);
        float o5 = fmaxf(a5 + sn * bfhi(sv.z) + b1.y, 0.f);
        float o6 = fmaxf(a6 + sn * bflo(sv.w) + b1.z, 0.f);
        float o7 = fmaxf(a7 + sn * bfhi(sv.w) + b1.w, 0.f);
        uint4 ov;
        ov.x = (unsigned int)f2b(o0) | ((unsigned int)f2b(o1) << 16);
        ov.y = (unsigned int)f2b(o2) | ((unsigned int)f2b(o3) << 16);
        ov.z = (unsigned int)f2b(o4) | ((unsigned int)f2b(o5) << 16);
        ov.w = (unsigned int)f2b(o6) | ((unsigned int)f2b(o7) << 16);
        *(uint4*)((char*)out + (size_t)node * 256 + fl * 16) = ov;
    }
}

// ---------------- segment-sum pool (batch sorted: flush on change) ----------------
__global__ __launch_bounds__(256) void k_pool(const unsigned short* __restrict__ h,
                                              const int* __restrict__ batch,
                                              float* __restrict__ out, int N) {
    int f4i = threadIdx.x & 31;
    int ln  = threadIdx.x >> 5;
    int base = blockIdx.x * 256;
    int end  = min(base + 256, N);
    const char* hb = (const char*)h;
    float sx = 0.f, sy = 0.f, sz = 0.f, sw = 0.f;
    int cur = -1;
    for (int n = base + ln; n < end; n += 8) {
        int g = batch[n];
        if (g != cur) {
            if (cur >= 0) {
                float* op = &out[cur * 128 + f4i * 4];
                atomicAdd(op + 0, sx); atomicAdd(op + 1, sy);
                atomicAdd(op + 2, sz); atomicAdd(op + 3, sw);
            }
            cur = g; sx = sy = sz = sw = 0.f;
        }
        uint2 v = *(const uint2*)(hb + (size_t)n * 256 + f4i * 8);
        sx += bflo(v.x); sy += bfhi(v.x);
        sz += bflo(v.y); sw += bfhi(v.y);
    }
    if (cur >= 0) {
        float* op = &out[cur * 128 + f4i * 4];
        atomicAdd(op + 0, sx); atomicAdd(op + 1, sy);
        atomicAdd(op + 2, sz); atomicAdd(op + 3, sw);
    }
}

extern "C" void kernel_launch(void* const* d_in, const int* in_sizes, int n_in,
                              void* d_out, int out_size, void* d_ws, size_t ws_size,
                              hipStream_t stream) {
    const float* x   = (const float*)d_in[0];
    const int*   ei  = (const int*)d_in[1];
    const float* ew  = (const float*)d_in[2];
    const int*  batch= (const int*)d_in[3];
    const float* W1  = (const float*)d_in[4];
    const float* b1  = (const float*)d_in[5];
    const float* W2  = (const float*)d_in[6];
    const float* b2  = (const float*)d_in[7];
    const int E = in_sizes[2];
    const int N = in_sizes[3];
    const int* srcp = ei;
    const int* dstp = ei + E;

    char* wsb = (char*)d_ws;
    size_t off = 0;
    auto alloc = [&](size_t bytes) -> void* {
        void* p = wsb + off;
        off += (bytes + 255) & ~(size_t)255;
        return p;
    };
    int2*  pairs = (int2*)alloc((size_t)E * 8);                        // 12.8 MB
    unsigned short* xb = (unsigned short*)alloc((size_t)N * 128 * 2);  // 25.6 MB
    unsigned short* hA = (unsigned short*)alloc((size_t)N * 128 * 2);  // 25.6 MB
    unsigned short* hB = (unsigned short*)alloc((size_t)N * 128 * 2);  // 25.6 MB
    unsigned long long* pack = (unsigned long long*)alloc((size_t)N * 8 * PSTRIDE); // 6.4 MB
    int*   posInNode = (int*)alloc((size_t)E * 4);                     // 6.4 MB
    float* dinv  = (float*)alloc((size_t)N * 4);
    int*   rs    = (int*)alloc((size_t)(N + 1) * 4);
    int*   bsum  = (int*)alloc(4096);
    unsigned short* W1t = (unsigned short*)alloc(128 * 128 * 2);
    unsigned short* W2t = (unsigned short*)alloc(128 * 128 * 2);

    const int HB = (E + 255) / 256;           // 6250 hist blocks
    const int n4 = N * 128 / 4;
    const int CB = (n4 + 255) / 256;          // 12500 cvt blocks
    const int FB = (E + 255) / 256;           // 6250 fill blocks
    const int GB = (N + 127) / 128;           // 782 gemm blocks
    const int nbScan = (N + 1023) / 1024;     // 98

    hipMemsetAsync(pack, 0, (size_t)N * 8 * PSTRIDE, stream);
    k_front<<<HB + CB + 128, 256, 0, stream>>>(dstp, ew, pack, posInNode, E,
                                               x, xb, n4, W1, W1t, W2, W2t, HB, CB);
    k_scan1<<<nbScan, 256, 0, stream>>>(pack, dinv, rs, bsum, N);
    k_scan2<<<1, 64, 0, stream>>>(bsum, nbScan);
    k_scan3<<<(N + 255) / 256, 256, 0, stream>>>(rs, bsum, N, E);
    k_fill_gemm<<<FB + GB, 256, 0, stream>>>(srcp, dstp, ew, dinv, rs, posInNode,
                                             pairs, E, xb, W1t, hA, N, FB);

    k_gather<<<(N + 3) / 4, 256, 0, stream>>>(hA, rs, pairs, dinv, b1, hB, N);
    k_gemm  <<<GB, 256, 0, stream>>>(hB, W2t, hA, N);
    k_gather<<<(N + 3) / 4, 256, 0, stream>>>(hA, rs, pairs, dinv, b2, hB, N);

    hipMemsetAsync(d_out, 0, (size_t)out_size * 4, stream);
    k_pool <<<(N + 255) / 256, 256, 0, stream>>>(hB, batch, (float*)d_out, N);
}

// Round 5
// 377.721 us; speedup vs baseline: 1.9341x; 1.0844x over previous
//
#include <hip/hip_runtime.h>
#include <hip/hip_bf16.h>

// GCN 2-layer, bf16 h + MFMA GEMM, LDS-bucketed CSR build (no per-edge global atomics):
// front[count(LDS-hist) | cvt_W | cvt_x] -> bscan -> [partition | gemm1] -> csr(per-bucket)
// -> gather1 -> gemm2 -> gather2 -> pool(LDS slots)
// N = 100000, E = 1600000, F = 128, G = 64. Bucket = 256 consecutive dst nodes.

typedef __attribute__((ext_vector_type(8))) short bf16x8;
typedef __attribute__((ext_vector_type(4))) float f32x4;

__device__ __forceinline__ unsigned short f2b(float f) {   // fp32 -> bf16 RNE
    unsigned int u = __float_as_uint(f);
    return (unsigned short)((u + 0x7fffu + ((u >> 16) & 1u)) >> 16);
}
__device__ __forceinline__ float bflo(unsigned int u) { return __uint_as_float(u << 16); }
__device__ __forceinline__ float bfhi(unsigned int u) { return __uint_as_float(u & 0xffff0000u); }

// ---------------- front: bucket-count (LDS hist) | cvt_W | cvt_x ----------------
__global__ __launch_bounds__(256) void k_front(const int* __restrict__ dst,
                                               int* __restrict__ bucketCnt, int E, int PB,
                                               const float* __restrict__ x,
                                               unsigned short* __restrict__ xb, int n4,
                                               const float* __restrict__ W1,
                                               unsigned short* __restrict__ W1t,
                                               const float* __restrict__ W2,
                                               unsigned short* __restrict__ W2t,
                                               int nbkt) {
    __shared__ unsigned int lcnt[512];
    int b = blockIdx.x, tid = threadIdx.x;
    if (b < PB) {                      // coarse count: 8192 edges per block
        for (int k = tid; k < nbkt; k += 256) lcnt[k] = 0;
        __syncthreads();
        int e0 = b * 8192;
        #pragma unroll
        for (int i = 0; i < 32; ++i) {
            int e = e0 + i * 256 + tid;
            if (e < E) atomicAdd(&lcnt[dst[e] >> 8], 1u);
        }
        __syncthreads();
        for (int k = tid; k < nbkt; k += 256) {
            unsigned int c = lcnt[k];
            if (c) atomicAdd(&bucketCnt[k], (int)c);
        }
    } else if (b < PB + 128) {         // W[128k][128n] fp32 -> Wt[128n][128k] bf16
        int wsel = b - PB;
        const float* W = (wsel < 64) ? W1 : W2;
        unsigned short* Wt = (wsel < 64) ? W1t : W2t;
        int idx = (wsel & 63) * 256 + tid;
        int k = idx >> 7, n = idx & 127;
        Wt[n * 128 + k] = f2b(W[idx]);
    } else {                           // x fp32 -> bf16
        int i = (b - PB - 128) * 256 + tid;
        if (i < n4) {
            float4 v = *(const float4*)&x[(size_t)i * 4];
            uint2 r;
            r.x = (unsigned int)f2b(v.x) | ((unsigned int)f2b(v.y) << 16);
            r.y = (unsigned int)f2b(v.z) | ((unsigned int)f2b(v.w) << 16);
            *(uint2*)&xb[(size_t)i * 4] = r;
        }
    }
}

// ---------------- bucket exclusive scan (single wave) ----------------
__global__ void k_bscan(const int* __restrict__ cnt, int* __restrict__ base,
                        int* __restrict__ cur, int nbkt, int E) {
    int lane = threadIdx.x;
    int carry = 0;
    for (int b0 = 0; b0 < nbkt; b0 += 64) {
        int i = b0 + lane;
        int v = (i < nbkt) ? cnt[i] : 0;
        int x = v;
        #pragma unroll
        for (int off = 1; off < 64; off <<= 1) {
            int y = __shfl_up(x, off);
            if (lane >= off) x += y;
        }
        int tot = __shfl(x, 63);
        if (i < nbkt) {
            int ex = carry + x - v;
            base[i] = ex;
            cur[i] = ex;
        }
        carry += tot;
    }
    if (lane == 0) base[nbkt] = E;
}

// ---------------- GEMM body ----------------
__device__ __forceinline__ void gemm_body(unsigned int* Wl,
                                          const unsigned short* __restrict__ A,
                                          const unsigned short* __restrict__ Wt,
                                          unsigned short* __restrict__ C,
                                          int nrows, int blk) {
    const int tid = threadIdx.x;
    const int row0 = blk * 128;
    {   // stage Wt swizzled: byte = n*256 + (koff ^ ((n&7)<<4))
        const unsigned int* Wg = (const unsigned int*)Wt;
        #pragma unroll
        for (int i = 0; i < 32; ++i) {
            int u = tid + 256 * i;
            int n = u >> 6, kp = u & 63;
            unsigned int val = Wg[u];
            *(unsigned int*)((char*)Wl + n * 256 + ((kp * 4) ^ ((n & 7) << 4))) = val;
        }
    }
    const int lane = tid & 63, wv = tid >> 6;
    const int m0 = row0 + wv * 32;
    const int lr = lane & 15, lg = lane >> 4;

    bf16x8 a[2][4];
    #pragma unroll
    for (int mi = 0; mi < 2; ++mi)
        #pragma unroll
        for (int kb = 0; kb < 4; ++kb) {
            int r = m0 + mi * 16 + lr;
            if (r < nrows)
                a[mi][kb] = *(const bf16x8*)&A[(size_t)r * 128 + kb * 32 + lg * 8];
            else
                a[mi][kb] = (bf16x8)0;
        }
    __syncthreads();

    f32x4 acc[2][8] = {};
    #pragma unroll
    for (int nb = 0; nb < 8; ++nb) {
        #pragma unroll
        for (int kb = 0; kb < 4; ++kb) {
            int n = nb * 16 + lr;
            int koff = kb * 64 + lg * 16;
            bf16x8 bfrag = *(const bf16x8*)((const char*)Wl + n * 256 + (koff ^ ((n & 7) << 4)));
            acc[0][nb] = __builtin_amdgcn_mfma_f32_16x16x32_bf16(a[0][kb], bfrag, acc[0][nb], 0, 0, 0);
            acc[1][nb] = __builtin_amdgcn_mfma_f32_16x16x32_bf16(a[1][kb], bfrag, acc[1][nb], 0, 0, 0);
        }
    }
    #pragma unroll
    for (int mi = 0; mi < 2; ++mi) {
        int rbase = m0 + mi * 16 + lg * 4;
        #pragma unroll
        for (int nb = 0; nb < 8; ++nb) {
            int col = nb * 16 + lr;
            #pragma unroll
            for (int r = 0; r < 4; ++r) {
                int row = rbase + r;
                if (row < nrows) C[(size_t)row * 128 + col] = f2b(acc[mi][nb][r]);
            }
        }
    }
}

__global__ __launch_bounds__(256) void k_gemm(const unsigned short* __restrict__ A,
                                              const unsigned short* __restrict__ Wt,
                                              unsigned short* __restrict__ C, int nrows) {
    __shared__ unsigned int Wl[8192];
    gemm_body(Wl, A, Wt, C, nrows, blockIdx.x);
}

// ---------------- partition edges into buckets | gemm1 ----------------
__global__ __launch_bounds__(256) void k_part(const int* __restrict__ src,
                                              const int* __restrict__ dst,
                                              const float* __restrict__ w,
                                              int* __restrict__ bucketCur,
                                              uint2* __restrict__ recs, int E, int PB,
                                              const unsigned short* __restrict__ A,
                                              const unsigned short* __restrict__ Wt,
                                              unsigned short* __restrict__ C, int nrows,
                                              int nbkt) {
    __shared__ unsigned int SH[8192];   // 32 KB (gemm W-tile; partition uses first 4 KB)
    int b = blockIdx.x, tid = threadIdx.x;
    if (b >= PB) { gemm_body(SH, A, Wt, C, nrows, b - PB); return; }
    unsigned int* lcnt  = SH;           // [512]
    unsigned int* gbase = SH + 512;     // [512]
    for (int k = tid; k < nbkt; k += 256) lcnt[k] = 0;
    __syncthreads();
    int e0 = b * 8192;
    #pragma unroll
    for (int i = 0; i < 32; ++i) {
        int e = e0 + i * 256 + tid;
        if (e < E) atomicAdd(&lcnt[dst[e] >> 8], 1u);
    }
    __syncthreads();
    for (int k = tid; k < nbkt; k += 256) {
        unsigned int c = lcnt[k];
        gbase[k] = c ? (unsigned int)atomicAdd(&bucketCur[k], (int)c) : 0u;
        lcnt[k] = 0;
    }
    __syncthreads();
    #pragma unroll
    for (int i = 0; i < 32; ++i) {
        int e = e0 + i * 256 + tid;
        if (e < E) {
            int d = dst[e];
            int k = d >> 8;
            unsigned int pos = atomicAdd(&lcnt[k], 1u);
            uint2 r;
            r.x = ((unsigned int)(d & 255) << 24) | (unsigned int)src[e];  // src < 2^24
            r.y = __float_as_uint(w[e]);
            recs[gbase[k] + pos] = r;
        }
    }
}

// ---------------- per-bucket CSR: deg/dinv, rs, ordered pairs ----------------
__global__ __launch_bounds__(256) void k_csr(const uint2* __restrict__ recs,
                                             const int* __restrict__ bucketBase,
                                             float* __restrict__ dinv,
                                             int* __restrict__ rs,
                                             int2* __restrict__ pairs, int N, int E) {
    __shared__ float wdeg[256];
    __shared__ unsigned int pcnt[256];
    __shared__ float dinvL[256];
    __shared__ unsigned int lbase[256];
    __shared__ unsigned int wtot[4];
    int b = blockIdx.x, tid = threadIdx.x;
    int beg = bucketBase[b], endI = bucketBase[b + 1];
    int nodeBase = b << 8;
    wdeg[tid] = 0.f; pcnt[tid] = 0u;
    __syncthreads();
    for (int i = beg + tid; i < endI; i += 256) {
        uint2 r = recs[i];
        int k = r.x >> 24;
        atomicAdd(&wdeg[k], __uint_as_float(r.y));
        atomicAdd(&pcnt[k], 1u);
    }
    __syncthreads();
    unsigned int v = pcnt[tid];
    float dv = rsqrtf(wdeg[tid] + 1.0f);   // +1 self-loop
    dinvL[tid] = dv;
    int node = nodeBase + tid;
    if (node < N) dinv[node] = dv;
    int lane = tid & 63, wv = tid >> 6;
    unsigned int x = v;
    #pragma unroll
    for (int off = 1; off < 64; off <<= 1) {
        unsigned int y = (unsigned int)__shfl_up((int)x, off);
        if (lane >= off) x += y;
    }
    if (lane == 63) wtot[wv] = x;
    __syncthreads();
    unsigned int woff = 0;
    for (int wI = 0; wI < wv; ++wI) woff += wtot[wI];
    unsigned int excl = woff + x - v;
    lbase[tid] = excl;
    if (node < N) rs[node] = beg + (int)excl;
    if (node == N - 1) rs[N] = E;
    pcnt[tid] = 0u;
    __syncthreads();
    for (int i = beg + tid; i < endI; i += 256) {
        uint2 r = recs[i];
        int k = r.x >> 24;
        unsigned int pos = atomicAdd(&pcnt[k], 1u);
        int2 pr;
        pr.x = (int)(r.x & 0xFFFFFFu);
        pr.y = __float_as_int(__uint_as_float(r.y) * dinvL[k]);   // w * dinv[dst]
        pairs[beg + (int)lbase[k] + (int)pos] = pr;
    }
}

// ---------------- gather: pairs hold w*dinv[dst]; multiply dinv[src] inline ----------------
#define ACC8(v, wt)                                            \
    a0 += wt * bflo(v.x); a1 += wt * bfhi(v.x);                \
    a2 += wt * bflo(v.y); a3 += wt * bfhi(v.y);                \
    a4 += wt * bflo(v.z); a5 += wt * bfhi(v.z);                \
    a6 += wt * bflo(v.w); a7 += wt * bfhi(v.w);

__global__ __launch_bounds__(256) void k_gather(const unsigned short* __restrict__ h,
                                                const int* __restrict__ rs,
                                                const int2* __restrict__ pairs,
                                                const float* __restrict__ dinv,
                                                const float* __restrict__ bias,
                                                unsigned short* __restrict__ out, int N) {
    int node = blockIdx.x * 4 + (threadIdx.x >> 6);
    if (node >= N) return;
    int lane = threadIdx.x & 63;
    int g  = lane >> 4;          // edge group 0..3
    int fl = lane & 15;          // 16B segment of the 256B row
    const char* hb = (const char*)h;
    int p = rs[node], end = rs[node + 1];
    float a0 = 0.f, a1 = 0.f, a2 = 0.f, a3 = 0.f;
    float a4 = 0.f, a5 = 0.f, a6 = 0.f, a7 = 0.f;
    for (; p + 8 <= end; p += 8) {         // 8 edges/iter: 2 independent 1KB row-loads
        int2 prA = pairs[p + g];
        int2 prB = pairs[p + 4 + g];
        float wA = __int_as_float(prA.y) * dinv[prA.x];
        float wB = __int_as_float(prB.y) * dinv[prB.x];
        uint4 vA = *(const uint4*)(hb + (size_t)prA.x * 256 + fl * 16);
        uint4 vB = *(const uint4*)(hb + (size_t)prB.x * 256 + fl * 16);
        ACC8(vA, wA);
        ACC8(vB, wB);
    }
    if (p + 4 <= end) {
        int2 pr = pairs[p + g];
        float wt = __int_as_float(pr.y) * dinv[pr.x];
        uint4 v = *(const uint4*)(hb + (size_t)pr.x * 256 + fl * 16);
        ACC8(v, wt);
        p += 4;
    }
    int r = end - p;                       // 0..3 tail
    if (r > 0) {
        int idx = p + (g < r ? g : 0);
        int2 pr = pairs[idx];
        float wt = (g < r) ? __int_as_float(pr.y) * dinv[pr.x] : 0.f;
        uint4 v = *(const uint4*)(hb + (size_t)pr.x * 256 + fl * 16);
        ACC8(v, wt);
    }
    a0 += __shfl_xor(a0, 16); a1 += __shfl_xor(a1, 16);
    a2 += __shfl_xor(a2, 16); a3 += __shfl_xor(a3, 16);
    a4 += __shfl_xor(a4, 16); a5 += __shfl_xor(a5, 16);
    a6 += __shfl_xor(a6, 16); a7 += __shfl_xor(a7, 16);
    a0 += __shfl_xor(a0, 32); a1 += __shfl_xor(a1, 32);
    a2 += __shfl_xor(a2, 32); a3 += __shfl_xor(a3, 32);
    a4 += __shfl_xor(a4, 32); a5 += __shfl_xor(a5, 32);
    a6 += __shfl_xor(a6, 32); a7 += __shfl_xor(a7, 32);
    if (g == 0) {   // epilogue: self-loop + bias + relu, store 16B
        float di = dinv[node];
        float sn = di * di;
        uint4 sv = *(const uint4*)(hb + (size_t)node * 256 + fl * 16);
        float4 b0 = *(const float4*)&bias[fl * 8];
        float4 b1 = *(const float4*)&bias[fl * 8 + 4];
        float o0 = fmaxf(a0 + sn * bflo(sv.x) + b0.x, 0.f);
        float o1 = fmaxf(a1 + sn * bfhi(sv.x) + b0.y, 0.f);
        float o2 = fmaxf(a2 + sn * bflo(sv.y) + b0.z, 0.f);
        float o3 = fmaxf(a3 + sn * bfhi(sv.y) + b0.w, 0.f);
        float o4 = fmaxf(a4 + sn * bflo(sv.z) + b1.x, 0.f);
        float o5 = fmaxf(a5 + sn * bfhi(sv.z) + b1.y, 0.f);
        float o6 = fmaxf(a6 + sn * bflo(sv.w) + b1.z, 0.f);
        float o7 = fmaxf(a7 + sn * bfhi(sv.w) + b1.w, 0.f);
        uint4 ov;
        ov.x = (unsigned int)f2b(o0) | ((unsigned int)f2b(o1) << 16);
        ov.y = (unsigned int)f2b(o2) | ((unsigned int)f2b(o3) << 16);
        ov.z = (unsigned int)f2b(o4) | ((unsigned int)f2b(o5) << 16);
        ov.w = (unsigned int)f2b(o6) | ((unsigned int)f2b(o7) << 16);
        *(uint4*)((char*)out + (size_t)node * 256 + fl * 16) = ov;
    }
}

// ---------------- pool: per-thread runs -> LDS graph slots -> 128 atomics/slot ----------------
__global__ __launch_bounds__(256) void k_pool(const unsigned short* __restrict__ h,
                                              const int* __restrict__ batch,
                                              float* __restrict__ out, int N) {
    __shared__ float acc[8][128];
    __shared__ int smax;
    int tid = threadIdx.x;
    int base = blockIdx.x * 256;
    if (base >= N) return;
    if (tid == 0) smax = -1;
    for (int i = tid; i < 1024; i += 256) ((float*)acc)[i] = 0.f;
    int gmin = batch[base];
    __syncthreads();
    int f4i = tid & 31, ln = tid >> 5;
    int end = min(base + 256, N);
    const char* hb = (const char*)h;
    float sx = 0.f, sy = 0.f, sz = 0.f, sw = 0.f;
    int cur = -1;
    for (int n = base + ln; n < end; n += 8) {
        int g = batch[n];
        if (g != cur) {
            if (cur >= 0) {
                int slot = cur - gmin;
                if (slot < 8) {
                    atomicAdd(&acc[slot][f4i * 4 + 0], sx);
                    atomicAdd(&acc[slot][f4i * 4 + 1], sy);
                    atomicAdd(&acc[slot][f4i * 4 + 2], sz);
                    atomicAdd(&acc[slot][f4i * 4 + 3], sw);
                    atomicMax(&smax, slot);
                } else {   // safety fallback (pathological tiny graphs)
                    float* op = &out[cur * 128 + f4i * 4];
                    atomicAdd(op + 0, sx); atomicAdd(op + 1, sy);
                    atomicAdd(op + 2, sz); atomicAdd(op + 3, sw);
                }
            }
            cur = g; sx = sy = sz = sw = 0.f;
        }
        uint2 v = *(const uint2*)(hb + (size_t)n * 256 + f4i * 8);
        sx += bflo(v.x); sy += bfhi(v.x);
        sz += bflo(v.y); sw += bfhi(v.y);
    }
    if (cur >= 0) {
        int slot = cur - gmin;
        if (slot < 8) {
            atomicAdd(&acc[slot][f4i * 4 + 0], sx);
            atomicAdd(&acc[slot][f4i * 4 + 1], sy);
            atomicAdd(&acc[slot][f4i * 4 + 2], sz);
            atomicAdd(&acc[slot][f4i * 4 + 3], sw);
            atomicMax(&smax, slot);
        } else {
            float* op = &out[cur * 128 + f4i * 4];
            atomicAdd(op + 0, sx); atomicAdd(op + 1, sy);
            atomicAdd(op + 2, sz); atomicAdd(op + 3, sw);
        }
    }
    __syncthreads();
    int sm = smax;
    for (int s = 0; s <= sm; ++s)
        if (tid < 128) atomicAdd(&out[(gmin + s) * 128 + tid], acc[s][tid]);
}

extern "C" void kernel_launch(void* const* d_in, const int* in_sizes, int n_in,
                              void* d_out, int out_size, void* d_ws, size_t ws_size,
                              hipStream_t stream) {
    const float* x   = (const float*)d_in[0];
    const int*   ei  = (const int*)d_in[1];
    const float* ew  = (const float*)d_in[2];
    const int*  batch= (const int*)d_in[3];
    const float* W1  = (const float*)d_in[4];
    const float* b1  = (const float*)d_in[5];
    const float* W2  = (const float*)d_in[6];
    const float* b2  = (const float*)d_in[7];
    const int E = in_sizes[2];
    const int N = in_sizes[3];
    const int* srcp = ei;
    const int* dstp = ei + E;

    char* wsb = (char*)d_ws;
    size_t off = 0;
    auto alloc = [&](size_t bytes) -> void* {
        void* p = wsb + off;
        off += (bytes + 255) & ~(size_t)255;
        return p;
    };
    uint2* recs  = (uint2*)alloc((size_t)E * 8);                       // 12.8 MB
    int2*  pairs = (int2*)alloc((size_t)E * 8);                        // 12.8 MB
    unsigned short* xb = (unsigned short*)alloc((size_t)N * 128 * 2);  // 25.6 MB
    unsigned short* hA = (unsigned short*)alloc((size_t)N * 128 * 2);  // 25.6 MB
    unsigned short* hB = (unsigned short*)alloc((size_t)N * 128 * 2);  // 25.6 MB
    float* dinv  = (float*)alloc((size_t)N * 4);
    int*   rs    = (int*)alloc((size_t)(N + 1) * 4);
    const int nbkt = (N + 255) >> 8;                                   // 391
    int* bucketCnt  = (int*)alloc((size_t)(nbkt + 1) * 4);
    int* bucketBase = (int*)alloc((size_t)(nbkt + 1) * 4);
    int* bucketCur  = (int*)alloc((size_t)(nbkt + 1) * 4);
    unsigned short* W1t = (unsigned short*)alloc(128 * 128 * 2);
    unsigned short* W2t = (unsigned short*)alloc(128 * 128 * 2);

    const int PB = (E + 8191) / 8192;         // 196 partition/count blocks
    const int n4 = N * 128 / 4;
    const int CB = (n4 + 255) / 256;          // 12500 cvt blocks
    const int GB = (N + 127) / 128;           // 782 gemm blocks

    hipMemsetAsync(bucketCnt, 0, (size_t)nbkt * 4, stream);
    k_front<<<PB + 128 + CB, 256, 0, stream>>>(dstp, bucketCnt, E, PB,
                                               x, xb, n4, W1, W1t, W2, W2t, nbkt);
    k_bscan<<<1, 64, 0, stream>>>(bucketCnt, bucketBase, bucketCur, nbkt, E);
    k_part<<<PB + GB, 256, 0, stream>>>(srcp, dstp, ew, bucketCur, recs, E, PB,
                                        xb, W1t, hA, N, nbkt);
    k_csr<<<nbkt, 256, 0, stream>>>(recs, bucketBase, dinv, rs, pairs, N, E);

    k_gather<<<(N + 3) / 4, 256, 0, stream>>>(hA, rs, pairs, dinv, b1, hB, N);
    k_gemm  <<<GB, 256, 0, stream>>>(hB, W2t, hA, N);
    k_gather<<<(N + 3) / 4, 256, 0, stream>>>(hA, rs, pairs, dinv, b2, hB, N);

    hipMemsetAsync(d_out, 0, (size_t)out_size * 4, stream);
    k_pool<<<(N + 255) / 256, 256, 0, stream>>>(hB, batch, (float*)d_out, N);
}

// Round 7
// 370.627 us; speedup vs baseline: 1.9711x; 1.0191x over previous
//
#include <hip/hip_runtime.h>
#include <hip/hip_bf16.h>

// GCN 2-layer, bf16 h + MFMA GEMM, LDS-staged counting-sort CSR:
// memset -> front[count | cvt_W] -> bscan -> [part(LDS-staged runs) | gemm1(fp32 A)]
// -> deg(dinv,rs) -> pairs(full norm, coalesced) -> gather1 -> gemm2 -> gather2 -> pool
// N = 100000, E = 1600000, F = 128, G = 64. Bucket = 256 consecutive dst nodes.

typedef __attribute__((ext_vector_type(8))) short bf16x8;
typedef __attribute__((ext_vector_type(4))) float f32x4;

__device__ __forceinline__ float4 ld4(const float* p) { return *(const float4*)p; }
__device__ __forceinline__ unsigned short f2b(float f) {   // fp32 -> bf16 RNE
    unsigned int u = __float_as_uint(f);
    return (unsigned short)((u + 0x7fffu + ((u >> 16) & 1u)) >> 16);
}
__device__ __forceinline__ float bflo(unsigned int u) { return __uint_as_float(u << 16); }
__device__ __forceinline__ float bfhi(unsigned int u) { return __uint_as_float(u & 0xffff0000u); }

// ---------------- front: bucket-count (LDS hist) | cvt_W ----------------
__global__ __launch_bounds__(256) void k_front(const int* __restrict__ dst,
                                               int* __restrict__ bucketCnt, int E, int PB,
                                               const float* __restrict__ W1,
                                               unsigned short* __restrict__ W1t,
                                               const float* __restrict__ W2,
                                               unsigned short* __restrict__ W2t, int nbkt) {
    __shared__ unsigned int lcnt[512];
    int b = blockIdx.x, tid = threadIdx.x;
    if (b < PB) {
        for (int k = tid; k < 512; k += 256) lcnt[k] = 0;
        __syncthreads();
        int e0 = b * 8192;
        #pragma unroll
        for (int i = 0; i < 32; ++i) {
            int e = e0 + i * 256 + tid;
            if (e < E) atomicAdd(&lcnt[dst[e] >> 8], 1u);
        }
        __syncthreads();
        for (int k = tid; k < nbkt; k += 256) {
            unsigned int c = lcnt[k];
            if (c) atomicAdd(&bucketCnt[k], (int)c);
        }
    } else {                           // W[128k][128n] fp32 -> Wt[128n][128k] bf16
        int wsel = b - PB;
        const float* W = (wsel < 64) ? W1 : W2;
        unsigned short* Wt = (wsel < 64) ? W1t : W2t;
        int idx = (wsel & 63) * 256 + tid;
        int k = idx >> 7, n = idx & 127;
        Wt[n * 128 + k] = f2b(W[idx]);
    }
}

// ---------------- bucket exclusive scan (single wave) ----------------
__global__ void k_bscan(const int* __restrict__ cnt, int* __restrict__ base,
                        int* __restrict__ cur, int nbkt, int E) {
    int lane = threadIdx.x;
    int carry = 0;
    for (int b0 = 0; b0 < nbkt; b0 += 64) {
        int i = b0 + lane;
        int v = (i < nbkt) ? cnt[i] : 0;
        int x = v;
        #pragma unroll
        for (int off = 1; off < 64; off <<= 1) {
            int y = __shfl_up(x, off);
            if (lane >= off) x += y;
        }
        int tot = __shfl(x, 63);
        if (i < nbkt) {
            int ex = carry + x - v;
            base[i] = ex;
            cur[i] = ex;
        }
        carry += tot;
    }
    if (lane == 0) base[nbkt] = E;
}

// ---------------- GEMM body (F32A: read A as fp32, cvt in-register) ----------------
template<bool F32A>
__device__ __forceinline__ void gemm_body(unsigned int* Wl, const void* __restrict__ Av,
                                          const unsigned short* __restrict__ Wt,
                                          unsigned short* __restrict__ C,
                                          int nrows, int blk) {
    const int tid = threadIdx.x;
    const int row0 = blk * 128;
    {   // stage Wt swizzled: byte = n*256 + (koff ^ ((n&7)<<4))
        const unsigned int* Wg = (const unsigned int*)Wt;
        #pragma unroll
        for (int i = 0; i < 32; ++i) {
            int u = tid + 256 * i;
            int n = u >> 6, kp = u & 63;
            unsigned int val = Wg[u];
            *(unsigned int*)((char*)Wl + n * 256 + ((kp * 4) ^ ((n & 7) << 4))) = val;
        }
    }
    const int lane = tid & 63, wv = tid >> 6;
    const int m0 = row0 + wv * 32;
    const int lr = lane & 15, lg = lane >> 4;

    bf16x8 a[2][4];
    #pragma unroll
    for (int mi = 0; mi < 2; ++mi)
        #pragma unroll
        for (int kb = 0; kb < 4; ++kb) {
            int r = m0 + mi * 16 + lr;
            if (r < nrows) {
                if (F32A) {
                    const float* ap = (const float*)Av + (size_t)r * 128 + kb * 32 + lg * 8;
                    float4 u = ld4(ap), v = ld4(ap + 4);
                    bf16x8 t;
                    t[0] = (short)f2b(u.x); t[1] = (short)f2b(u.y);
                    t[2] = (short)f2b(u.z); t[3] = (short)f2b(u.w);
                    t[4] = (short)f2b(v.x); t[5] = (short)f2b(v.y);
                    t[6] = (short)f2b(v.z); t[7] = (short)f2b(v.w);
                    a[mi][kb] = t;
                } else {
                    a[mi][kb] = *(const bf16x8*)((const unsigned short*)Av +
                                                 (size_t)r * 128 + kb * 32 + lg * 8);
                }
            } else a[mi][kb] = (bf16x8)0;
        }
    __syncthreads();

    f32x4 acc[2][8] = {};
    #pragma unroll
    for (int nb = 0; nb < 8; ++nb) {
        #pragma unroll
        for (int kb = 0; kb < 4; ++kb) {
            int n = nb * 16 + lr;
            int koff = kb * 64 + lg * 16;
            bf16x8 bfrag = *(const bf16x8*)((const char*)Wl + n * 256 + (koff ^ ((n & 7) << 4)));
            acc[0][nb] = __builtin_amdgcn_mfma_f32_16x16x32_bf16(a[0][kb], bfrag, acc[0][nb], 0, 0, 0);
            acc[1][nb] = __builtin_amdgcn_mfma_f32_16x16x32_bf16(a[1][kb], bfrag, acc[1][nb], 0, 0, 0);
        }
    }
    // C/D: col = lane&15, row = (lane>>4)*4 + reg
    #pragma unroll
    for (int mi = 0; mi < 2; ++mi) {
        int rbase = m0 + mi * 16 + lg * 4;
        #pragma unroll
        for (int nb = 0; nb < 8; ++nb) {
            int col = nb * 16 + lr;
            #pragma unroll
            for (int r = 0; r < 4; ++r) {
                int row = rbase + r;
                if (row < nrows) C[(size_t)row * 128 + col] = f2b(acc[mi][nb][r]);
            }
        }
    }
}

// ---------------- fused: LDS-staged partition | gemm1 (fp32 A) ----------------
__global__ __launch_bounds__(256) void k_part_gemm(const int* __restrict__ src,
                                                   const int* __restrict__ dst,
                                                   const float* __restrict__ w,
                                                   int* __restrict__ bucketCur,
                                                   uint2* __restrict__ recs, int E, int PB,
                                                   int nbkt,
                                                   const float* __restrict__ x,
                                                   const unsigned short* __restrict__ W1t,
                                                   unsigned short* __restrict__ hA, int N) {
    __shared__ unsigned long long SH8[9000];   // 72 KB
    int b = blockIdx.x, tid = threadIdx.x;
    if (b >= PB) {
        gemm_body<true>((unsigned int*)SH8, x, W1t, hA, N, b - PB);
        return;
    }
    uint2* lrec = (uint2*)SH8;                          // 64 KB: bucket-ordered records
    unsigned int* lcnt  = (unsigned int*)(SH8 + 8192);  // 512
    unsigned int* gbase = lcnt + 512;                   // 512
    unsigned int* loff  = gbase + 512;                  // 512
    unsigned int* wtot  = loff + 512;                   // 4

    for (int k = tid; k < 512; k += 256) lcnt[k] = 0;
    __syncthreads();
    int e0 = b * 8192;
    #pragma unroll
    for (int i = 0; i < 32; ++i) {
        int e = e0 + i * 256 + tid;
        if (e < E) atomicAdd(&lcnt[dst[e] >> 8], 1u);
    }
    __syncthreads();
    // block-level exclusive scan over 512 buckets (2 per thread)
    unsigned int c0 = lcnt[2 * tid], c1 = lcnt[2 * tid + 1];
    unsigned int v = c0 + c1;
    int lane = tid & 63, wv = tid >> 6;
    unsigned int xs = v;
    #pragma unroll
    for (int off = 1; off < 64; off <<= 1) {
        unsigned int y = (unsigned int)__shfl_up((int)xs, off);
        if (lane >= off) xs += y;
    }
    if (lane == 63) wtot[wv] = xs;
    __syncthreads();
    unsigned int woff = 0;
    for (int wI = 0; wI < wv; ++wI) woff += wtot[wI];
    unsigned int excl = woff + xs - v;
    loff[2 * tid] = excl;
    loff[2 * tid + 1] = excl + c0;
    if (c0) gbase[2 * tid] = (unsigned int)atomicAdd(&bucketCur[2 * tid], (int)c0);
    if (c1) gbase[2 * tid + 1] = (unsigned int)atomicAdd(&bucketCur[2 * tid + 1], (int)c1);
    lcnt[2 * tid] = 0; lcnt[2 * tid + 1] = 0;
    __syncthreads();
    // scatter into LDS (bucket-ordered image)
    #pragma unroll
    for (int i = 0; i < 32; ++i) {
        int e = e0 + i * 256 + tid;
        if (e < E) {
            int d = dst[e];
            int k = d >> 8;
            unsigned int pos = atomicAdd(&lcnt[k], 1u);
            uint2 r;
            r.x = ((unsigned int)(d & 255) << 24) | (unsigned int)src[e];  // src < 2^24
            r.y = __float_as_uint(w[e]);
            lrec[loff[k] + pos] = r;
        }
    }
    __syncthreads();
    // drain: per-wave bucket runs -> contiguous global writes
    for (int k = wv; k < nbkt; k += 4) {
        unsigned int c = lcnt[k];
        if (!c) continue;
        unsigned int gb = gbase[k], lo = loff[k];
        for (unsigned int j = (unsigned int)lane; j < c; j += 64)
            recs[gb + j] = lrec[lo + j];
    }
}

// ---------------- per-bucket degree -> dinv, rs ----------------
__global__ __launch_bounds__(256) void k_deg(const uint2* __restrict__ recs,
                                             const int* __restrict__ bucketBase,
                                             float* __restrict__ dinv,
                                             int* __restrict__ rs, int N, int E) {
    __shared__ float wdeg[256];
    __shared__ unsigned int pcnt[256];
    __shared__ unsigned int wtot[4];
    int b = blockIdx.x, tid = threadIdx.x;
    int beg = bucketBase[b], end = bucketBase[b + 1];
    wdeg[tid] = 0.f; pcnt[tid] = 0u;
    __syncthreads();
    for (int i = beg + tid; i < end; i += 256) {
        uint2 r = recs[i];
        int k = r.x >> 24;
        atomicAdd(&wdeg[k], __uint_as_float(r.y));
        atomicAdd(&pcnt[k], 1u);
    }
    __syncthreads();
    unsigned int v = pcnt[tid];
    float dv = rsqrtf(wdeg[tid] + 1.0f);   // +1 self-loop
    int node = (b << 8) + tid;
    if (node < N) dinv[node] = dv;
    int lane = tid & 63, wv = tid >> 6;
    unsigned int xs = v;
    #pragma unroll
    for (int off = 1; off < 64; off <<= 1) {
        unsigned int y = (unsigned int)__shfl_up((int)xs, off);
        if (lane >= off) xs += y;
    }
    if (lane == 63) wtot[wv] = xs;
    __syncthreads();
    unsigned int woff = 0;
    for (int wI = 0; wI < wv; ++wI) woff += wtot[wI];
    unsigned int excl = woff + xs - v;
    if (node < N) rs[node] = beg + (int)excl;
    if (node == N - 1) rs[N] = E;
}

// ---------------- per-bucket pairs write (full norm folded, coalesced) ----------------
__global__ __launch_bounds__(256) void k_pairs(const uint2* __restrict__ recs,
                                               const int* __restrict__ bucketBase,
                                               const float* __restrict__ dinv,
                                               const int* __restrict__ rs,
                                               int2* __restrict__ pairs, int N) {
    __shared__ uint2 lp[8192];          // 64 KB staged pairs image
    __shared__ unsigned int pcnt[256];
    __shared__ float dinvL[256];
    __shared__ unsigned int lbase[256];
    int b = blockIdx.x, tid = threadIdx.x;
    int beg = bucketBase[b], end = bucketBase[b + 1];
    int cnt = end - beg;
    int node = (b << 8) + tid;
    pcnt[tid] = 0u;
    dinvL[tid] = (node < N) ? dinv[node] : 0.f;
    lbase[tid] = (node < N) ? (unsigned int)(rs[node] - beg) : 0u;
    __syncthreads();
    if (cnt <= 8192) {
        for (int i = beg + tid; i < end; i += 256) {
            uint2 r = recs[i];
            int k = (int)(r.x >> 24);
            int s = (int)(r.x & 0xFFFFFFu);
            unsigned int pos = atomicAdd(&pcnt[k], 1u);
            uint2 pr;
            pr.x = (unsigned int)s;
            pr.y = __float_as_uint(__uint_as_float(r.y) * dinvL[k] * dinv[s]);
            lp[lbase[k] + pos] = pr;
        }
        __syncthreads();
        for (int i = tid; i < cnt; i += 256)
            *(uint2*)&pairs[beg + i] = lp[i];
    } else {    // fallback: direct scatter (pathological bucket)
        for (int i = beg + tid; i < end; i += 256) {
            uint2 r = recs[i];
            int k = (int)(r.x >> 24);
            int s = (int)(r.x & 0xFFFFFFu);
            unsigned int pos = atomicAdd(&pcnt[k], 1u);
            int2 pr;
            pr.x = s;
            pr.y = __float_as_int(__uint_as_float(r.y) * dinvL[k] * dinv[s]);
            pairs[beg + (int)lbase[k] + (int)pos] = pr;
        }
    }
}

__global__ __launch_bounds__(256) void k_gemm(const unsigned short* __restrict__ A,
                                              const unsigned short* __restrict__ Wt,
                                              unsigned short* __restrict__ C, int nrows) {
    __shared__ unsigned int Wl[8192];
    gemm_body<false>(Wl, A, Wt, C, nrows, blockIdx.x);
}

// ---------------- gather: 1 wave/node, 4 groups x 16 lanes, 16-edge unroll ----------------
#define ACC8(v, wt)                                            \
    a0 += wt * bflo(v.x); a1 += wt * bfhi(v.x);                \
    a2 += wt * bflo(v.y); a3 += wt * bfhi(v.y);                \
    a4 += wt * bflo(v.z); a5 += wt * bfhi(v.z);                \
    a6 += wt * bflo(v.w); a7 += wt * bfhi(v.w);

__global__ __launch_bounds__(256) void k_gather(const unsigned short* __restrict__ h,
                                                const int* __restrict__ rs,
                                                const int2* __restrict__ pairs,
                                                const float* __restrict__ dinv,
                                                const float* __restrict__ bias,
                                                unsigned short* __restrict__ out, int N) {
    int node = blockIdx.x * 4 + (threadIdx.x >> 6);
    if (node >= N) return;
    int lane = threadIdx.x & 63;
    int g  = lane >> 4;          // edge group 0..3
    int fl = lane & 15;          // 16B segment of the 256B row
    const char* hb = (const char*)h;
    int p = rs[node], end = rs[node + 1];
    float a0 = 0.f, a1 = 0.f, a2 = 0.f, a3 = 0.f;
    float a4 = 0.f, a5 = 0.f, a6 = 0.f, a7 = 0.f;
    for (; p + 16 <= end; p += 16) {       // 4 independent 1KB row-loads in flight
        int2 prA = pairs[p + g];
        int2 prB = pairs[p + 4 + g];
        int2 prC = pairs[p + 8 + g];
        int2 prD = pairs[p + 12 + g];
        float wA = __int_as_float(prA.y), wB = __int_as_float(prB.y);
        float wC = __int_as_float(prC.y), wD = __int_as_float(prD.y);
        uint4 vA = *(const uint4*)(hb + (size_t)prA.x * 256 + fl * 16);
        uint4 vB = *(const uint4*)(hb + (size_t)prB.x * 256 + fl * 16);
        uint4 vC = *(const uint4*)(hb + (size_t)prC.x * 256 + fl * 16);
        uint4 vD = *(const uint4*)(hb + (size_t)prD.x * 256 + fl * 16);
        ACC8(vA, wA); ACC8(vB, wB); ACC8(vC, wC); ACC8(vD, wD);
    }
    for (; p + 4 <= end; p += 4) {
        int2 pr = pairs[p + g];
        float wt = __int_as_float(pr.y);
        uint4 v = *(const uint4*)(hb + (size_t)pr.x * 256 + fl * 16);
        ACC8(v, wt);
    }
    int r = end - p;                       // 0..3 tail
    if (r > 0) {
        int idx = p + (g < r ? g : 0);
        int2 pr = pairs[idx];
        float wt = (g < r) ? __int_as_float(pr.y) : 0.f;
        uint4 v = *(const uint4*)(hb + (size_t)pr.x * 256 + fl * 16);
        ACC8(v, wt);
    }
    a0 += __shfl_xor(a0, 16); a1 += __shfl_xor(a1, 16);
    a2 += __shfl_xor(a2, 16); a3 += __shfl_xor(a3, 16);
    a4 += __shfl_xor(a4, 16); a5 += __shfl_xor(a5, 16);
    a6 += __shfl_xor(a6, 16); a7 += __shfl_xor(a7, 16);
    a0 += __shfl_xor(a0, 32); a1 += __shfl_xor(a1, 32);
    a2 += __shfl_xor(a2, 32); a3 += __shfl_xor(a3, 32);
    a4 += __shfl_xor(a4, 32); a5 += __shfl_xor(a5, 32);
    a6 += __shfl_xor(a6, 32); a7 += __shfl_xor(a7, 32);
    if (g == 0) {   // epilogue: self-loop + bias + relu, store 16B
        float di = dinv[node];
        float sn = di * di;
        uint4 sv = *(const uint4*)(hb + (size_t)node * 256 + fl * 16);
        float4 b0 = *(const float4*)&bias[fl * 8];
        float4 b1 = *(const float4*)&bias[fl * 8 + 4];
        float o0 = fmaxf(a0 + sn * bflo(sv.x) + b0.x, 0.f);
        float o1 = fmaxf(a1 + sn * bfhi(sv.x) + b0.y, 0.f);
        float o2 = fmaxf(a2 + sn * bflo(sv.y) + b0.z, 0.f);
        float o3 = fmaxf(a3 + sn * bfhi(sv.y) + b0.w, 0.f);
        float o4 = fmaxf(a4 + sn * bflo(sv.z) + b1.x, 0.f);
        float o5 = fmaxf(a5 + sn * bfhi(sv.z) + b1.y, 0.f);
        float o6 = fmaxf(a6 + sn * bflo(sv.w) + b1.z, 0.f);
        float o7 = fmaxf(a7 + sn * bfhi(sv.w) + b1.w, 0.f);
        uint4 ov;
        ov.x = (unsigned int)f2b(o0) | ((unsigned int)f2b(o1) << 16);
        ov.y = (unsigned int)f2b(o2) | ((unsigned int)f2b(o3) << 16);
        ov.z = (unsigned int)f2b(o4) | ((unsigned int)f2b(o5) << 16);
        ov.w = (unsigned int)f2b(o6) | ((unsigned int)f2b(o7) << 16);
        *(uint4*)((char*)out + (size_t)node * 256 + fl * 16) = ov;
    }
}

// ---------------- pool: per-thread runs -> LDS graph slots -> 128 atomics/slot ----------------
__global__ __launch_bounds__(256) void k_pool(const unsigned short* __restrict__ h,
                                              const int* __restrict__ batch,
                                              float* __restrict__ out, int N) {
    __shared__ float acc[8][128];
    __shared__ int smax;
    int tid = threadIdx.x;
    int base = blockIdx.x * 256;
    if (base >= N) return;
    if (tid == 0) smax = -1;
    for (int i = tid; i < 1024; i += 256) ((float*)acc)[i] = 0.f;
    int gmin = batch[base];
    __syncthreads();
    int f4i = tid & 31, ln = tid >> 5;
    int end = min(base + 256, N);
    const char* hb = (const char*)h;
    float sx = 0.f, sy = 0.f, sz = 0.f, sw = 0.f;
    int cur = -1;
    for (int n = base + ln; n < end; n += 8) {
        int g = batch[n];
        if (g != cur) {
            if (cur >= 0) {
                int slot = cur - gmin;
                if (slot < 8) {
                    atomicAdd(&acc[slot][f4i * 4 + 0], sx);
                    atomicAdd(&acc[slot][f4i * 4 + 1], sy);
                    atomicAdd(&acc[slot][f4i * 4 + 2], sz);
                    atomicAdd(&acc[slot][f4i * 4 + 3], sw);
                    atomicMax(&smax, slot);
                } else {
                    float* op = &out[cur * 128 + f4i * 4];
                    atomicAdd(op + 0, sx); atomicAdd(op + 1, sy);
                    atomicAdd(op + 2, sz); atomicAdd(op + 3, sw);
                }
            }
            cur = g; sx = sy = sz = sw = 0.f;
        }
        uint2 v = *(const uint2*)(hb + (size_t)n * 256 + f4i * 8);
        sx += bflo(v.x); sy += bfhi(v.x);
        sz += bflo(v.y); sw += bfhi(v.y);
    }
    if (cur >= 0) {
        int slot = cur - gmin;
        if (slot < 8) {
            atomicAdd(&acc[slot][f4i * 4 + 0], sx);
            atomicAdd(&acc[slot][f4i * 4 + 1], sy);
            atomicAdd(&acc[slot][f4i * 4 + 2], sz);
            atomicAdd(&acc[slot][f4i * 4 + 3], sw);
            atomicMax(&smax, slot);
        } else {
            float* op = &out[cur * 128 + f4i * 4];
            atomicAdd(op + 0, sx); atomicAdd(op + 1, sy);
            atomicAdd(op + 2, sz); atomicAdd(op + 3, sw);
        }
    }
    __syncthreads();
    int sm = smax;
    for (int s = 0; s <= sm; ++s)
        if (tid < 128) atomicAdd(&out[(gmin + s) * 128 + tid], acc[s][tid]);
}

extern "C" void kernel_launch(void* const* d_in, const int* in_sizes, int n_in,
                              void* d_out, int out_size, void* d_ws, size_t ws_size,
                              hipStream_t stream) {
    const float* x   = (const float*)d_in[0];
    const int*   ei  = (const int*)d_in[1];
    const float* ew  = (const float*)d_in[2];
    const int*  batch= (const int*)d_in[3];
    const float* W1  = (const float*)d_in[4];
    const float* b1  = (const float*)d_in[5];
    const float* W2  = (const float*)d_in[6];
    const float* b2  = (const float*)d_in[7];
    const int E = in_sizes[2];
    const int N = in_sizes[3];
    const int* srcp = ei;
    const int* dstp = ei + E;

    char* wsb = (char*)d_ws;
    size_t off = 0;
    auto alloc = [&](size_t bytes) -> void* {
        void* p = wsb + off;
        off += (bytes + 255) & ~(size_t)255;
        return p;
    };
    uint2* recs  = (uint2*)alloc((size_t)E * 8);                       // 12.8 MB
    int2*  pairs = (int2*)alloc((size_t)E * 8);                        // 12.8 MB
    unsigned short* hA = (unsigned short*)alloc((size_t)N * 128 * 2);  // 25.6 MB
    unsigned short* hB = (unsigned short*)alloc((size_t)N * 128 * 2);  // 25.6 MB
    float* dinv  = (float*)alloc((size_t)N * 4);
    int*   rs    = (int*)alloc((size_t)(N + 1) * 4);
    const int nbkt = (N + 255) >> 8;                                   // 391
    int* bucketCnt  = (int*)alloc((size_t)(nbkt + 1) * 4);
    int* bucketBase = (int*)alloc((size_t)(nbkt + 1) * 4);
    int* bucketCur  = (int*)alloc((size_t)(nbkt + 1) * 4);
    unsigned short* W1t = (unsigned short*)alloc(128 * 128 * 2);
    unsigned short* W2t = (unsigned short*)alloc(128 * 128 * 2);

    const int PB = (E + 8191) / 8192;         // 196 partition/count blocks
    const int GB = (N + 127) / 128;           // 782 gemm blocks

    hipMemsetAsync(bucketCnt, 0, (size_t)nbkt * 4, stream);
    k_front<<<PB + 128, 256, 0, stream>>>(dstp, bucketCnt, E, PB, W1, W1t, W2, W2t, nbkt);
    k_bscan<<<1, 64, 0, stream>>>(bucketCnt, bucketBase, bucketCur, nbkt, E);
    k_part_gemm<<<PB + GB, 256, 0, stream>>>(srcp, dstp, ew, bucketCur, recs, E, PB, nbkt,
                                             x, W1t, hA, N);
    k_deg  <<<nbkt, 256, 0, stream>>>(recs, bucketBase, dinv, rs, N, E);
    k_pairs<<<nbkt, 256, 0, stream>>>(recs, bucketBase, dinv, rs, pairs, N);

    k_gather<<<(N + 3) / 4, 256, 0, stream>>>(hA, rs, pairs, dinv, b1, hB, N);
    k_gemm  <<<GB, 256, 0, stream>>>(hB, W2t, hA, N);
    k_gather<<<(N + 3) / 4, 256, 0, stream>>>(hA, rs, pairs, dinv, b2, hB, N);

    hipMemsetAsync(d_out, 0, (size_t)out_size * 4, stream);
    k_pool<<<(N + 255) / 256, 256, 0, stream>>>(hB, batch, (float*)d_out, N);
}

// Round 8
// 366.761 us; speedup vs baseline: 1.9919x; 1.0105x over previous
//
#include <hip/hip_runtime.h>
#include <hip/hip_bf16.h>

// GCN 2-layer, bf16 h + MFMA GEMM, LDS-staged counting-sort CSR (compact 4B descriptors):
// memset -> front[count | cvt_W] -> bscan -> [part(16KB img, 4096 edges/blk) | gemm1(fp32 A)]
// -> deg(dinv,rs) -> pairs(full norm, coalesced) -> gather1 -> gemm2 -> gather2 -> pool
// N = 100000, E = 1600000, F = 128, G = 64. Bucket = 256 consecutive dst nodes.

typedef __attribute__((ext_vector_type(8))) short bf16x8;
typedef __attribute__((ext_vector_type(4))) float f32x4;

__device__ __forceinline__ float4 ld4(const float* p) { return *(const float4*)p; }
__device__ __forceinline__ unsigned short f2b(float f) {   // fp32 -> bf16 RNE
    unsigned int u = __float_as_uint(f);
    return (unsigned short)((u + 0x7fffu + ((u >> 16) & 1u)) >> 16);
}
__device__ __forceinline__ float bflo(unsigned int u) { return __uint_as_float(u << 16); }
__device__ __forceinline__ float bfhi(unsigned int u) { return __uint_as_float(u & 0xffff0000u); }

// ---------------- front: bucket-count (LDS hist) | cvt_W ----------------
__global__ __launch_bounds__(256) void k_front(const int* __restrict__ dst,
                                               int* __restrict__ bucketCnt, int E, int PB,
                                               const float* __restrict__ W1,
                                               unsigned short* __restrict__ W1t,
                                               const float* __restrict__ W2,
                                               unsigned short* __restrict__ W2t, int nbkt) {
    __shared__ unsigned int lcnt[512];
    int b = blockIdx.x, tid = threadIdx.x;
    if (b < PB) {
        for (int k = tid; k < 512; k += 256) lcnt[k] = 0;
        __syncthreads();
        int e0 = b * 8192;
        #pragma unroll
        for (int i = 0; i < 32; ++i) {
            int e = e0 + i * 256 + tid;
            if (e < E) atomicAdd(&lcnt[dst[e] >> 8], 1u);
        }
        __syncthreads();
        for (int k = tid; k < nbkt; k += 256) {
            unsigned int c = lcnt[k];
            if (c) atomicAdd(&bucketCnt[k], (int)c);
        }
    } else {                           // W[128k][128n] fp32 -> Wt[128n][128k] bf16
        int wsel = b - PB;
        const float* W = (wsel < 64) ? W1 : W2;
        unsigned short* Wt = (wsel < 64) ? W1t : W2t;
        int idx = (wsel & 63) * 256 + tid;
        int k = idx >> 7, n = idx & 127;
        Wt[n * 128 + k] = f2b(W[idx]);
    }
}

// ---------------- bucket exclusive scan (single wave) ----------------
__global__ void k_bscan(const int* __restrict__ cnt, int* __restrict__ base,
                        int* __restrict__ cur, int nbkt, int E) {
    int lane = threadIdx.x;
    int carry = 0;
    for (int b0 = 0; b0 < nbkt; b0 += 64) {
        int i = b0 + lane;
        int v = (i < nbkt) ? cnt[i] : 0;
        int x = v;
        #pragma unroll
        for (int off = 1; off < 64; off <<= 1) {
            int y = __shfl_up(x, off);
            if (lane >= off) x += y;
        }
        int tot = __shfl(x, 63);
        if (i < nbkt) {
            int ex = carry + x - v;
            base[i] = ex;
            cur[i] = ex;
        }
        carry += tot;
    }
    if (lane == 0) base[nbkt] = E;
}

// ---------------- GEMM body (F32A: read A as fp32, cvt in-register) ----------------
template<bool F32A>
__device__ __forceinline__ void gemm_body(unsigned int* Wl, const void* __restrict__ Av,
                                          const unsigned short* __restrict__ Wt,
                                          unsigned short* __restrict__ C,
                                          int nrows, int blk) {
    const int tid = threadIdx.x;
    const int row0 = blk * 128;
    {   // stage Wt swizzled: byte = n*256 + (koff ^ ((n&7)<<4))
        const unsigned int* Wg = (const unsigned int*)Wt;
        #pragma unroll
        for (int i = 0; i < 32; ++i) {
            int u = tid + 256 * i;
            int n = u >> 6, kp = u & 63;
            unsigned int val = Wg[u];
            *(unsigned int*)((char*)Wl + n * 256 + ((kp * 4) ^ ((n & 7) << 4))) = val;
        }
    }
    const int lane = tid & 63, wv = tid >> 6;
    const int m0 = row0 + wv * 32;
    const int lr = lane & 15, lg = lane >> 4;

    bf16x8 a[2][4];
    #pragma unroll
    for (int mi = 0; mi < 2; ++mi)
        #pragma unroll
        for (int kb = 0; kb < 4; ++kb) {
            int r = m0 + mi * 16 + lr;
            if (r < nrows) {
                if (F32A) {
                    const float* ap = (const float*)Av + (size_t)r * 128 + kb * 32 + lg * 8;
                    float4 u = ld4(ap), v = ld4(ap + 4);
                    bf16x8 t;
                    t[0] = (short)f2b(u.x); t[1] = (short)f2b(u.y);
                    t[2] = (short)f2b(u.z); t[3] = (short)f2b(u.w);
                    t[4] = (short)f2b(v.x); t[5] = (short)f2b(v.y);
                    t[6] = (short)f2b(v.z); t[7] = (short)f2b(v.w);
                    a[mi][kb] = t;
                } else {
                    a[mi][kb] = *(const bf16x8*)((const unsigned short*)Av +
                                                 (size_t)r * 128 + kb * 32 + lg * 8);
                }
            } else a[mi][kb] = (bf16x8)0;
        }
    __syncthreads();

    f32x4 acc[2][8] = {};
    #pragma unroll
    for (int nb = 0; nb < 8; ++nb) {
        #pragma unroll
        for (int kb = 0; kb < 4; ++kb) {
            int n = nb * 16 + lr;
            int koff = kb * 64 + lg * 16;
            bf16x8 bfrag = *(const bf16x8*)((const char*)Wl + n * 256 + (koff ^ ((n & 7) << 4)));
            acc[0][nb] = __builtin_amdgcn_mfma_f32_16x16x32_bf16(a[0][kb], bfrag, acc[0][nb], 0, 0, 0);
            acc[1][nb] = __builtin_amdgcn_mfma_f32_16x16x32_bf16(a[1][kb], bfrag, acc[1][nb], 0, 0, 0);
        }
    }
    // C/D: col = lane&15, row = (lane>>4)*4 + reg
    #pragma unroll
    for (int mi = 0; mi < 2; ++mi) {
        int rbase = m0 + mi * 16 + lg * 4;
        #pragma unroll
        for (int nb = 0; nb < 8; ++nb) {
            int col = nb * 16 + lr;
            #pragma unroll
            for (int r = 0; r < 4; ++r) {
                int row = rbase + r;
                if (row < nrows) C[(size_t)row * 128 + col] = f2b(acc[mi][nb][r]);
            }
        }
    }
}

// ---------------- fused: compact LDS-staged partition | gemm1 (fp32 A) ----------------
// Partition: 4096 edges/block. img[i] = (local_e << 9) | bucket. 32 KB total shared.
__global__ __launch_bounds__(256) void k_part_gemm(const int* __restrict__ src,
                                                   const int* __restrict__ dst,
                                                   const float* __restrict__ w,
                                                   int* __restrict__ bucketCur,
                                                   uint2* __restrict__ recs, int E, int PB,
                                                   int nbkt,
                                                   const float* __restrict__ x,
                                                   const unsigned short* __restrict__ W1t,
                                                   unsigned short* __restrict__ hA, int N) {
    __shared__ unsigned int SH[8192];   // 32 KB (gemm Wl; partition uses ~22 KB)
    int b = blockIdx.x, tid = threadIdx.x;
    if (b >= PB) {
        gemm_body<true>(SH, x, W1t, hA, N, b - PB);
        return;
    }
    unsigned int* img   = SH;            // [4096] packed (le<<9)|k
    unsigned int* lcnt  = SH + 4096;     // [512]
    unsigned int* gbase = lcnt + 512;    // [512]
    unsigned int* loff  = gbase + 512;   // [512]
    unsigned int* wtot  = loff + 512;    // [4]

    for (int k = tid; k < 512; k += 256) lcnt[k] = 0;
    __syncthreads();
    int e0 = b * 4096;
    #pragma unroll
    for (int i = 0; i < 16; ++i) {
        int e = e0 + i * 256 + tid;
        if (e < E) atomicAdd(&lcnt[dst[e] >> 8], 1u);
    }
    __syncthreads();
    // block-level exclusive scan over 512 buckets (2 per thread)
    unsigned int c0 = lcnt[2 * tid], c1 = lcnt[2 * tid + 1];
    unsigned int v = c0 + c1;
    int lane = tid & 63, wv = tid >> 6;
    unsigned int xs = v;
    #pragma unroll
    for (int off = 1; off < 64; off <<= 1) {
        unsigned int y = (unsigned int)__shfl_up((int)xs, off);
        if (lane >= off) xs += y;
    }
    if (lane == 63) wtot[wv] = xs;
    __syncthreads();
    unsigned int woff = 0;
    for (int wI = 0; wI < wv; ++wI) woff += wtot[wI];
    unsigned int excl = woff + xs - v;
    loff[2 * tid] = excl;
    loff[2 * tid + 1] = excl + c0;
    if (c0) gbase[2 * tid] = (unsigned int)atomicAdd(&bucketCur[2 * tid], (int)c0);
    if (c1) gbase[2 * tid + 1] = (unsigned int)atomicAdd(&bucketCur[2 * tid + 1], (int)c1);
    lcnt[2 * tid] = 0; lcnt[2 * tid + 1] = 0;
    __syncthreads();
    // scatter compact descriptors into bucket-ordered LDS image (4B, ~2-way conflicts = free)
    #pragma unroll
    for (int i = 0; i < 16; ++i) {
        int e = e0 + i * 256 + tid;
        if (e < E) {
            int k = dst[e] >> 8;
            unsigned int pos = atomicAdd(&lcnt[k], 1u);
            img[loff[k] + pos] = ((unsigned int)(i * 256 + tid) << 9) | (unsigned int)k;
        }
    }
    __syncthreads();
    // drain: consecutive img slots -> bucket-run-ordered global writes (L1-hot re-reads)
    int total = min(4096, E - e0);
    for (int i = tid; i < total; i += 256) {
        unsigned int d = img[i];
        int k = (int)(d & 511u);
        int e = e0 + (int)(d >> 9);
        uint2 r;
        r.x = ((unsigned int)(dst[e] & 255) << 24) | (unsigned int)src[e];  // src < 2^24
        r.y = __float_as_uint(w[e]);
        recs[gbase[k] + (unsigned int)i - loff[k]] = r;
    }
}

// ---------------- per-bucket degree -> dinv, rs ----------------
__global__ __launch_bounds__(256) void k_deg(const uint2* __restrict__ recs,
                                             const int* __restrict__ bucketBase,
                                             float* __restrict__ dinv,
                                             int* __restrict__ rs, int N, int E) {
    __shared__ float wdeg[256];
    __shared__ unsigned int pcnt[256];
    __shared__ unsigned int wtot[4];
    int b = blockIdx.x, tid = threadIdx.x;
    int beg = bucketBase[b], end = bucketBase[b + 1];
    wdeg[tid] = 0.f; pcnt[tid] = 0u;
    __syncthreads();
    for (int i = beg + tid; i < end; i += 256) {
        uint2 r = recs[i];
        int k = r.x >> 24;
        atomicAdd(&wdeg[k], __uint_as_float(r.y));
        atomicAdd(&pcnt[k], 1u);
    }
    __syncthreads();
    unsigned int v = pcnt[tid];
    float dv = rsqrtf(wdeg[tid] + 1.0f);   // +1 self-loop
    int node = (b << 8) + tid;
    if (node < N) dinv[node] = dv;
    int lane = tid & 63, wv = tid >> 6;
    unsigned int xs = v;
    #pragma unroll
    for (int off = 1; off < 64; off <<= 1) {
        unsigned int y = (unsigned int)__shfl_up((int)xs, off);
        if (lane >= off) xs += y;
    }
    if (lane == 63) wtot[wv] = xs;
    __syncthreads();
    unsigned int woff = 0;
    for (int wI = 0; wI < wv; ++wI) woff += wtot[wI];
    unsigned int excl = woff + xs - v;
    if (node < N) rs[node] = beg + (int)excl;
    if (node == N - 1) rs[N] = E;
}

// ---------------- per-bucket pairs write (full norm folded, coalesced) ----------------
__global__ __launch_bounds__(256) void k_pairs(const uint2* __restrict__ recs,
                                               const int* __restrict__ bucketBase,
                                               const float* __restrict__ dinv,
                                               const int* __restrict__ rs,
                                               int2* __restrict__ pairs, int N) {
    __shared__ uint2 lp[8192];          // 64 KB staged pairs image
    __shared__ unsigned int pcnt[256];
    __shared__ float dinvL[256];
    __shared__ unsigned int lbase[256];
    int b = blockIdx.x, tid = threadIdx.x;
    int beg = bucketBase[b], end = bucketBase[b + 1];
    int cnt = end - beg;
    int node = (b << 8) + tid;
    pcnt[tid] = 0u;
    dinvL[tid] = (node < N) ? dinv[node] : 0.f;
    lbase[tid] = (node < N) ? (unsigned int)(rs[node] - beg) : 0u;
    __syncthreads();
    if (cnt <= 8192) {
        for (int i = beg + tid; i < end; i += 256) {
            uint2 r = recs[i];
            int k = (int)(r.x >> 24);
            int s = (int)(r.x & 0xFFFFFFu);
            unsigned int pos = atomicAdd(&pcnt[k], 1u);
            uint2 pr;
            pr.x = (unsigned int)s;
            pr.y = __float_as_uint(__uint_as_float(r.y) * dinvL[k] * dinv[s]);
            lp[lbase[k] + pos] = pr;
        }
        __syncthreads();
        for (int i = tid; i < cnt; i += 256)
            *(uint2*)&pairs[beg + i] = lp[i];
    } else {    // fallback: direct scatter (pathological bucket)
        for (int i = beg + tid; i < end; i += 256) {
            uint2 r = recs[i];
            int k = (int)(r.x >> 24);
            int s = (int)(r.x & 0xFFFFFFu);
            unsigned int pos = atomicAdd(&pcnt[k], 1u);
            int2 pr;
            pr.x = s;
            pr.y = __float_as_int(__uint_as_float(r.y) * dinvL[k] * dinv[s]);
            pairs[beg + (int)lbase[k] + (int)pos] = pr;
        }
    }
}

__global__ __launch_bounds__(256) void k_gemm(const unsigned short* __restrict__ A,
                                              const unsigned short* __restrict__ Wt,
                                              unsigned short* __restrict__ C, int nrows) {
    __shared__ unsigned int Wl[8192];
    gemm_body<false>(Wl, A, Wt, C, nrows, blockIdx.x);
}

// ---------------- gather: 1 wave/node, 4 groups x 16 lanes, 16-edge unroll ----------------
#define ACC8(v, wt)                                            \
    a0 += wt * bflo(v.x); a1 += wt * bfhi(v.x);                \
    a2 += wt * bflo(v.y); a3 += wt * bfhi(v.y);                \
    a4 += wt * bflo(v.z); a5 += wt * bfhi(v.z);                \
    a6 += wt * bflo(v.w); a7 += wt * bfhi(v.w);

__global__ __launch_bounds__(256) void k_gather(const unsigned short* __restrict__ h,
                                                const int* __restrict__ rs,
                                                const int2* __restrict__ pairs,
                                                const float* __restrict__ dinv,
                                                const float* __restrict__ bias,
                                                unsigned short* __restrict__ out, int N) {
    int node = blockIdx.x * 4 + (threadIdx.x >> 6);
    if (node >= N) return;
    int lane = threadIdx.x & 63;
    int g  = lane >> 4;          // edge group 0..3
    int fl = lane & 15;          // 16B segment of the 256B row
    const char* hb = (const char*)h;
    int p = rs[node], end = rs[node + 1];
    float a0 = 0.f, a1 = 0.f, a2 = 0.f, a3 = 0.f;
    float a4 = 0.f, a5 = 0.f, a6 = 0.f, a7 = 0.f;
    for (; p + 16 <= end; p += 16) {       // 4 independent 1KB row-loads in flight
        int2 prA = pairs[p + g];
        int2 prB = pairs[p + 4 + g];
        int2 prC = pairs[p + 8 + g];
        int2 prD = pairs[p + 12 + g];
        float wA = __int_as_float(prA.y), wB = __int_as_float(prB.y);
        float wC = __int_as_float(prC.y), wD = __int_as_float(prD.y);
        uint4 vA = *(const uint4*)(hb + (size_t)prA.x * 256 + fl * 16);
        uint4 vB = *(const uint4*)(hb + (size_t)prB.x * 256 + fl * 16);
        uint4 vC = *(const uint4*)(hb + (size_t)prC.x * 256 + fl * 16);
        uint4 vD = *(const uint4*)(hb + (size_t)prD.x * 256 + fl * 16);
        ACC8(vA, wA); ACC8(vB, wB); ACC8(vC, wC); ACC8(vD, wD);
    }
    for (; p + 4 <= end; p += 4) {
        int2 pr = pairs[p + g];
        float wt = __int_as_float(pr.y);
        uint4 v = *(const uint4*)(hb + (size_t)pr.x * 256 + fl * 16);
        ACC8(v, wt);
    }
    int r = end - p;                       // 0..3 tail
    if (r > 0) {
        int idx = p + (g < r ? g : 0);
        int2 pr = pairs[idx];
        float wt = (g < r) ? __int_as_float(pr.y) : 0.f;
        uint4 v = *(const uint4*)(hb + (size_t)pr.x * 256 + fl * 16);
        ACC8(v, wt);
    }
    a0 += __shfl_xor(a0, 16); a1 += __shfl_xor(a1, 16);
    a2 += __shfl_xor(a2, 16); a3 += __shfl_xor(a3, 16);
    a4 += __shfl_xor(a4, 16); a5 += __shfl_xor(a5, 16);
    a6 += __shfl_xor(a6, 16); a7 += __shfl_xor(a7, 16);
    a0 += __shfl_xor(a0, 32); a1 += __shfl_xor(a1, 32);
    a2 += __shfl_xor(a2, 32); a3 += __shfl_xor(a3, 32);
    a4 += __shfl_xor(a4, 32); a5 += __shfl_xor(a5, 32);
    a6 += __shfl_xor(a6, 32); a7 += __shfl_xor(a7, 32);
    if (g == 0) {   // epilogue: self-loop + bias + relu, store 16B
        float di = dinv[node];
        float sn = di * di;
        uint4 sv = *(const uint4*)(hb + (size_t)node * 256 + fl * 16);
        float4 b0 = *(const float4*)&bias[fl * 8];
        float4 b1 = *(const float4*)&bias[fl * 8 + 4];
        float o0 = fmaxf(a0 + sn * bflo(sv.x) + b0.x, 0.f);
        float o1 = fmaxf(a1 + sn * bfhi(sv.x) + b0.y, 0.f);
        float o2 = fmaxf(a2 + sn * bflo(sv.y) + b0.z, 0.f);
        float o3 = fmaxf(a3 + sn * bfhi(sv.y) + b0.w, 0.f);
        float o4 = fmaxf(a4 + sn * bflo(sv.z) + b1.x, 0.f);
        float o5 = fmaxf(a5 + sn * bfhi(sv.z) + b1.y, 0.f);
        float o6 = fmaxf(a6 + sn * bflo(sv.w) + b1.z, 0.f);
        float o7 = fmaxf(a7 + sn * bfhi(sv.w) + b1.w, 0.f);
        uint4 ov;
        ov.x = (unsigned int)f2b(o0) | ((unsigned int)f2b(o1) << 16);
        ov.y = (unsigned int)f2b(o2) | ((unsigned int)f2b(o3) << 16);
        ov.z = (unsigned int)f2b(o4) | ((unsigned int)f2b(o5) << 16);
        ov.w = (unsigned int)f2b(o6) | ((unsigned int)f2b(o7) << 16);
        *(uint4*)((char*)out + (size_t)node * 256 + fl * 16) = ov;
    }
}

// ---------------- pool: per-thread runs -> LDS graph slots -> 128 atomics/slot ----------------
__global__ __launch_bounds__(256) void k_pool(const unsigned short* __restrict__ h,
                                              const int* __restrict__ batch,
                                              float* __restrict__ out, int N) {
    __shared__ float acc[8][128];
    __shared__ int smax;
    int tid = threadIdx.x;
    int base = blockIdx.x * 256;
    if (base >= N) return;
    if (tid == 0) smax = -1;
    for (int i = tid; i < 1024; i += 256) ((float*)acc)[i] = 0.f;
    int gmin = batch[base];
    __syncthreads();
    int f4i = tid & 31, ln = tid >> 5;
    int end = min(base + 256, N);
    const char* hb = (const char*)h;
    float sx = 0.f, sy = 0.f, sz = 0.f, sw = 0.f;
    int cur = -1;
    for (int n = base + ln; n < end; n += 8) {
        int g = batch[n];
        if (g != cur) {
            if (cur >= 0) {
                int slot = cur - gmin;
                if (slot < 8) {
                    atomicAdd(&acc[slot][f4i * 4 + 0], sx);
                    atomicAdd(&acc[slot][f4i * 4 + 1], sy);
                    atomicAdd(&acc[slot][f4i * 4 + 2], sz);
                    atomicAdd(&acc[slot][f4i * 4 + 3], sw);
                    atomicMax(&smax, slot);
                } else {
                    float* op = &out[cur * 128 + f4i * 4];
                    atomicAdd(op + 0, sx); atomicAdd(op + 1, sy);
                    atomicAdd(op + 2, sz); atomicAdd(op + 3, sw);
                }
            }
            cur = g; sx = sy = sz = sw = 0.f;
        }
        uint2 v = *(const uint2*)(hb + (size_t)n * 256 + f4i * 8);
        sx += bflo(v.x); sy += bfhi(v.x);
        sz += bflo(v.y); sw += bfhi(v.y);
    }
    if (cur >= 0) {
        int slot = cur - gmin;
        if (slot < 8) {
            atomicAdd(&acc[slot][f4i * 4 + 0], sx);
            atomicAdd(&acc[slot][f4i * 4 + 1], sy);
            atomicAdd(&acc[slot][f4i * 4 + 2], sz);
            atomicAdd(&acc[slot][f4i * 4 + 3], sw);
            atomicMax(&smax, slot);
        } else {
            float* op = &out[cur * 128 + f4i * 4];
            atomicAdd(op + 0, sx); atomicAdd(op + 1, sy);
            atomicAdd(op + 2, sz); atomicAdd(op + 3, sw);
        }
    }
    __syncthreads();
    int sm = smax;
    for (int s = 0; s <= sm; ++s)
        if (tid < 128) atomicAdd(&out[(gmin + s) * 128 + tid], acc[s][tid]);
}

extern "C" void kernel_launch(void* const* d_in, const int* in_sizes, int n_in,
                              void* d_out, int out_size, void* d_ws, size_t ws_size,
                              hipStream_t stream) {
    const float* x   = (const float*)d_in[0];
    const int*   ei  = (const int*)d_in[1];
    const float* ew  = (const float*)d_in[2];
    const int*  batch= (const int*)d_in[3];
    const float* W1  = (const float*)d_in[4];
    const float* b1  = (const float*)d_in[5];
    const float* W2  = (const float*)d_in[6];
    const float* b2  = (const float*)d_in[7];
    const int E = in_sizes[2];
    const int N = in_sizes[3];
    const int* srcp = ei;
    const int* dstp = ei + E;

    char* wsb = (char*)d_ws;
    size_t off = 0;
    auto alloc = [&](size_t bytes) -> void* {
        void* p = wsb + off;
        off += (bytes + 255) & ~(size_t)255;
        return p;
    };
    uint2* recs  = (uint2*)alloc((size_t)E * 8);                       // 12.8 MB
    int2*  pairs = (int2*)alloc((size_t)E * 8);                        // 12.8 MB
    unsigned short* hA = (unsigned short*)alloc((size_t)N * 128 * 2);  // 25.6 MB
    unsigned short* hB = (unsigned short*)alloc((size_t)N * 128 * 2);  // 25.6 MB
    float* dinv  = (float*)alloc((size_t)N * 4);
    int*   rs    = (int*)alloc((size_t)(N + 1) * 4);
    const int nbkt = (N + 255) >> 8;                                   // 391
    int* bucketCnt  = (int*)alloc((size_t)(nbkt + 1) * 4);
    int* bucketBase = (int*)alloc((size_t)(nbkt + 1) * 4);
    int* bucketCur  = (int*)alloc((size_t)(nbkt + 1) * 4);
    unsigned short* W1t = (unsigned short*)alloc(128 * 128 * 2);
    unsigned short* W2t = (unsigned short*)alloc(128 * 128 * 2);

    const int CPB = (E + 8191) / 8192;        // 196 count blocks (front)
    const int PB  = (E + 4095) / 4096;        // 391 partition blocks
    const int GB  = (N + 127) / 128;          // 782 gemm blocks

    hipMemsetAsync(bucketCnt, 0, (size_t)nbkt * 4, stream);
    k_front<<<CPB + 128, 256, 0, stream>>>(dstp, bucketCnt, E, CPB, W1, W1t, W2, W2t, nbkt);
    k_bscan<<<1, 64, 0, stream>>>(bucketCnt, bucketBase, bucketCur, nbkt, E);
    k_part_gemm<<<PB + GB, 256, 0, stream>>>(srcp, dstp, ew, bucketCur, recs, E, PB, nbkt,
                                             x, W1t, hA, N);
    k_deg  <<<nbkt, 256, 0, stream>>>(recs, bucketBase, dinv, rs, N, E);
    k_pairs<<<nbkt, 256, 0, stream>>>(recs, bucketBase, dinv, rs, pairs, N);

    k_gather<<<(N + 3) / 4, 256, 0, stream>>>(hA, rs, pairs, dinv, b1, hB, N);
    k_gemm  <<<GB, 256, 0, stream>>>(hB, W2t, hA, N);
    k_gather<<<(N + 3) / 4, 256, 0, stream>>>(hA, rs, pairs, dinv, b2, hB, N);

    hipMemsetAsync(d_out, 0, (size_t)out_size * 4, stream);
    k_pool<<<(N + 255) / 256, 256, 0, stream>>>(hB, batch, (float*)d_out, N);
}